// Round 1
// baseline (662.194 us; speedup 1.0000x reference)
//
#include <hip/hip_runtime.h>
#include <hip/hip_bf16.h>
#include <math.h>

// ---------------------------------------------------------------------------
// TransformerBlock: B=8 T=1024 C=1024 H=16 d=64, bf16 MFMA compute, fp32 acc.
// ---------------------------------------------------------------------------

#define DEVI __device__ __forceinline__

typedef __attribute__((ext_vector_type(4))) float floatx4;
typedef __attribute__((ext_vector_type(8))) short shortx8;   // 8 bf16 = 4 VGPRs

DEVI ushort f2b(float f) {
    __hip_bfloat16 h = __float2bfloat16(f);
    return __builtin_bit_cast(ushort, h);
}

// ---------------------------------------------------------------------------
// Weight transpose + fp32->bf16 cast: src[R][C] fp32  ->  dst[C][R] bf16
// ---------------------------------------------------------------------------
__global__ void transp_kernel(const float* __restrict__ src,
                              ushort* __restrict__ dst, int R, int C) {
    __shared__ float tile[32][33];
    const int c0 = blockIdx.x * 32, r0 = blockIdx.y * 32;
    const int tx = threadIdx.x, ty = threadIdx.y;   // 32 x 8
#pragma unroll
    for (int i = 0; i < 32; i += 8)
        tile[ty + i][tx] = src[(size_t)(r0 + ty + i) * C + c0 + tx];
    __syncthreads();
#pragma unroll
    for (int i = 0; i < 32; i += 8)
        dst[(size_t)(c0 + ty + i) * R + r0 + tx] = f2b(tile[tx][ty + i]);
}

// ---------------------------------------------------------------------------
// LayerNorm over C=1024, one block (256 thr) per token. fp32 in, bf16 out.
// ---------------------------------------------------------------------------
__global__ __launch_bounds__(256)
void ln_kernel(const float* __restrict__ x, const float* __restrict__ w,
               const float* __restrict__ b, ushort* __restrict__ out) {
    __shared__ float red[8];
    const int m = blockIdx.x;
    const int tid = threadIdx.x;
    const float4 xv = *(const float4*)&x[(size_t)m * 1024 + tid * 4];
    float s  = xv.x + xv.y + xv.z + xv.w;
    float s2 = xv.x * xv.x + xv.y * xv.y + xv.z * xv.z + xv.w * xv.w;
#pragma unroll
    for (int o = 32; o >= 1; o >>= 1) {
        s  += __shfl_xor(s, o, 64);
        s2 += __shfl_xor(s2, o, 64);
    }
    const int wv_ = tid >> 6;
    if ((tid & 63) == 0) { red[wv_] = s; red[4 + wv_] = s2; }
    __syncthreads();
    s  = red[0] + red[1] + red[2] + red[3];
    s2 = red[4] + red[5] + red[6] + red[7];
    const float mu   = s * (1.0f / 1024.0f);
    const float var  = s2 * (1.0f / 1024.0f) - mu * mu;
    const float rstd = rsqrtf(var + 1e-5f);
    const float4 wv = *(const float4*)&w[tid * 4];
    const float4 bv = *(const float4*)&b[tid * 4];
    ushort o4[4];
    o4[0] = f2b((xv.x - mu) * rstd * wv.x + bv.x);
    o4[1] = f2b((xv.y - mu) * rstd * wv.y + bv.y);
    o4[2] = f2b((xv.z - mu) * rstd * wv.z + bv.z);
    o4[3] = f2b((xv.w - mu) * rstd * wv.w + bv.w);
    *(uint2*)&out[(size_t)m * 1024 + tid * 4] = *(uint2*)o4;
}

// ---------------------------------------------------------------------------
// GEMM: C[M][N] = A[M][K] @ Bt[N][K]^T (+bias, epilogue variants)
//   MODE 1: write bf16 to [B][H][T][d] heads layout (QKV)
//   MODE 2: fp32 out = resid + acc + bias (Wo residual / FFN2 residual)
//   MODE 3: bf16 out = gelu(acc + bias)   (FFN1)
// 128x128 block tile, BK=64, 4 waves each 64x64 via 4x4 of 16x16x32 MFMA.
// LDS rows padded to 72 bf16 (144B) -> 2-way bank aliasing only (free).
// ---------------------------------------------------------------------------
template <int MODE>
__global__ __launch_bounds__(256)
void gemm_bt(const ushort* __restrict__ A, const ushort* __restrict__ Bt,
             const float* __restrict__ bias, void* __restrict__ out,
             const float* __restrict__ resid, int M, int N, int K) {
    __shared__ ushort sA[128 * 72];
    __shared__ ushort sB[128 * 72];
    const int tid  = threadIdx.x;
    const int lane = tid & 63;
    const int wave = tid >> 6;
    const int quad = lane >> 4;
    const int l15  = lane & 15;
    const int wm   = (wave & 1) * 64;
    const int wn   = (wave >> 1) * 64;
    const int m0   = blockIdx.y * 128;
    const int n0   = blockIdx.x * 128;

    floatx4 acc[4][4] = {};

    const int srow = tid >> 3;          // 0..31
    const int scol = (tid & 7) * 8;     // 0..56
    const ushort* Ag = A  + (size_t)(m0 + srow) * K + scol;
    const ushort* Bg = Bt + (size_t)(n0 + srow) * K + scol;

    for (int k0 = 0; k0 < K; k0 += 64) {
        __syncthreads();
#pragma unroll
        for (int p = 0; p < 4; ++p) {
            const int r = srow + p * 32;
            *(uint4*)&sA[r * 72 + scol] = *(const uint4*)&Ag[(size_t)(p * 32) * K + k0];
            *(uint4*)&sB[r * 72 + scol] = *(const uint4*)&Bg[(size_t)(p * 32) * K + k0];
        }
        __syncthreads();
#pragma unroll
        for (int ks = 0; ks < 2; ++ks) {
            shortx8 af[4], bf[4];
#pragma unroll
            for (int i = 0; i < 4; ++i)
                af[i] = *(const shortx8*)&sA[(wm + i * 16 + l15) * 72 + ks * 32 + quad * 8];
#pragma unroll
            for (int j = 0; j < 4; ++j)
                bf[j] = *(const shortx8*)&sB[(wn + j * 16 + l15) * 72 + ks * 32 + quad * 8];
#pragma unroll
            for (int i = 0; i < 4; ++i)
#pragma unroll
                for (int j = 0; j < 4; ++j)
                    acc[i][j] = __builtin_amdgcn_mfma_f32_16x16x32_bf16(
                        af[i], bf[j], acc[i][j], 0, 0, 0);
        }
    }
    // epilogue: lane holds C[row=quad*4+r][col=l15] per 16x16 sub-tile
#pragma unroll
    for (int i = 0; i < 4; ++i) {
#pragma unroll
        for (int j = 0; j < 4; ++j) {
#pragma unroll
            for (int r = 0; r < 4; ++r) {
                const int gm = m0 + wm + i * 16 + quad * 4 + r;
                const int gn = n0 + wn + j * 16 + l15;
                float v = acc[i][j][r] + bias[gn];
                if constexpr (MODE == 1) {
                    const int bb = gm >> 10, t = gm & 1023;
                    const int h = gn >> 6, dd = gn & 63;
                    ((ushort*)out)[(((size_t)(bb * 16 + h) * 1024 + t) << 6) + dd] = f2b(v);
                } else if constexpr (MODE == 2) {
                    v += resid[(size_t)gm * N + gn];
                    ((float*)out)[(size_t)gm * N + gn] = v;
                } else if constexpr (MODE == 3) {
                    const float g = 0.5f * v * (1.0f + erff(v * 0.70710678f));
                    ((ushort*)out)[(size_t)gm * N + gn] = f2b(g);
                }
            }
        }
    }
}

// ---------------------------------------------------------------------------
// Flash-style causal attention. Q,K,V: [B*H][T=1024][64] bf16.
// Block = (b*16+h, 64-row q-tile); 4 waves x 16 q-rows; kv-tiles of 64.
// ctx out: [B][T][C] bf16 at col h*64+dim.
// ---------------------------------------------------------------------------
__global__ __launch_bounds__(256)
void attn_kernel(const ushort* __restrict__ Q, const ushort* __restrict__ Kk,
                 const ushort* __restrict__ V, ushort* __restrict__ ctx) {
    __shared__ ushort sK[64 * 72];
    __shared__ ushort sVt[64 * 72];
    __shared__ ushort sP[4][16 * 72];

    const int tid  = threadIdx.x;
    const int lane = tid & 63;
    const int wave = tid >> 6;
    const int quad = lane >> 4;
    const int l15  = lane & 15;

    const int qb = blockIdx.x & 15;      // q-tile index (T/64 = 16)
    const int bh = blockIdx.x >> 4;      // 0..127
    const size_t base = (size_t)bh * 1024 * 64;

    // Q fragments for this wave's 16 rows (A-operand layout)
    const int qrow = qb * 64 + wave * 16 + l15;
    shortx8 qf0 = *(const shortx8*)&Q[base + (size_t)qrow * 64 + quad * 8];
    shortx8 qf1 = *(const shortx8*)&Q[base + (size_t)qrow * 64 + 32 + quad * 8];

    float mstate[4], lstate[4];
    floatx4 oacc[4] = {};
#pragma unroll
    for (int r = 0; r < 4; ++r) { mstate[r] = -__builtin_inff(); lstate[r] = 0.0f; }

    const int srow = tid >> 3;          // 0..31
    const int scol = (tid & 7) * 8;     // 0..56

    for (int kt = 0; kt <= qb; ++kt) {
        __syncthreads();
        // stage K tile [64][64] and V^T tile [64 dims][64 t]
#pragma unroll
        for (int p = 0; p < 2; ++p) {
            const int r = srow + p * 32;
            const size_t g = base + (size_t)(kt * 64 + r) * 64 + scol;
            *(uint4*)&sK[r * 72 + scol] = *(const uint4*)&Kk[g];
            ushort vv[8];
            *(uint4*)vv = *(const uint4*)&V[g];
#pragma unroll
            for (int e = 0; e < 8; ++e)
                sVt[(scol + e) * 72 + r] = vv[e];
        }
        __syncthreads();

        // S = Q @ K^T  (16 x 64 per wave)
        floatx4 s[4];
#pragma unroll
        for (int nt = 0; nt < 4; ++nt) {
            shortx8 kf0 = *(const shortx8*)&sK[(nt * 16 + l15) * 72 + quad * 8];
            shortx8 kf1 = *(const shortx8*)&sK[(nt * 16 + l15) * 72 + 32 + quad * 8];
            floatx4 z = {};
            z = __builtin_amdgcn_mfma_f32_16x16x32_bf16(qf0, kf0, z, 0, 0, 0);
            z = __builtin_amdgcn_mfma_f32_16x16x32_bf16(qf1, kf1, z, 0, 0, 0);
            s[nt] = z;
        }
        // scale + causal mask (only the diagonal tile needs it)
#pragma unroll
        for (int nt = 0; nt < 4; ++nt)
#pragma unroll
            for (int r = 0; r < 4; ++r) {
                float sv = s[nt][r] * 0.125f;
                if (kt == qb) {
                    const int col = kt * 64 + nt * 16 + l15;
                    const int row = qb * 64 + wave * 16 + quad * 4 + r;
                    if (col > row) sv = -__builtin_inff();
                }
                s[nt][r] = sv;
            }
        // online softmax per row (rows live in 16-lane quad groups)
        float mnew[4], alpha[4];
#pragma unroll
        for (int r = 0; r < 4; ++r) {
            float mt = fmaxf(fmaxf(s[0][r], s[1][r]), fmaxf(s[2][r], s[3][r]));
#pragma unroll
            for (int o = 8; o >= 1; o >>= 1) mt = fmaxf(mt, __shfl_xor(mt, o, 64));
            mnew[r]  = fmaxf(mstate[r], mt);
            alpha[r] = __expf(mstate[r] - mnew[r]);
            mstate[r] = mnew[r];
        }
#pragma unroll
        for (int r = 0; r < 4; ++r) {
            float rs = 0.0f;
#pragma unroll
            for (int nt = 0; nt < 4; ++nt) {
                const float p = __expf(s[nt][r] - mnew[r]);
                s[nt][r] = p;
                rs += p;
            }
#pragma unroll
            for (int o = 8; o >= 1; o >>= 1) rs += __shfl_xor(rs, o, 64);
            lstate[r] = alpha[r] * lstate[r] + rs;
#pragma unroll
            for (int dt = 0; dt < 4; ++dt) oacc[dt][r] *= alpha[r];
        }
        // P (C-layout) -> LDS -> A-layout fragments
#pragma unroll
        for (int nt = 0; nt < 4; ++nt)
#pragma unroll
            for (int r = 0; r < 4; ++r)
                sP[wave][(quad * 4 + r) * 72 + nt * 16 + l15] = f2b(s[nt][r]);
        __syncthreads();
        shortx8 pf0 = *(const shortx8*)&sP[wave][l15 * 72 + quad * 8];
        shortx8 pf1 = *(const shortx8*)&sP[wave][l15 * 72 + 32 + quad * 8];
#pragma unroll
        for (int dt = 0; dt < 4; ++dt) {
            shortx8 v0 = *(const shortx8*)&sVt[(dt * 16 + l15) * 72 + quad * 8];
            shortx8 v1 = *(const shortx8*)&sVt[(dt * 16 + l15) * 72 + 32 + quad * 8];
            oacc[dt] = __builtin_amdgcn_mfma_f32_16x16x32_bf16(pf0, v0, oacc[dt], 0, 0, 0);
            oacc[dt] = __builtin_amdgcn_mfma_f32_16x16x32_bf16(pf1, v1, oacc[dt], 0, 0, 0);
        }
    }
    // normalize and write ctx
    const int bb = bh >> 4, h = bh & 15;
#pragma unroll
    for (int dt = 0; dt < 4; ++dt)
#pragma unroll
        for (int r = 0; r < 4; ++r) {
            const int t = qb * 64 + wave * 16 + quad * 4 + r;
            const int dim = dt * 16 + l15;
            const float v = oacc[dt][r] / lstate[r];
            ctx[((size_t)(bb * 1024 + t) * 1024) + h * 64 + dim] = f2b(v);
        }
}

// ---------------------------------------------------------------------------
// Launch
// ---------------------------------------------------------------------------
extern "C" void kernel_launch(void* const* d_in, const int* in_sizes, int n_in,
                              void* d_out, int out_size, void* d_ws, size_t ws_size,
                              hipStream_t stream) {
    const float* x    = (const float*)d_in[0];
    const float* ln1w = (const float*)d_in[2];
    const float* ln1b = (const float*)d_in[3];
    const float* ln2w = (const float*)d_in[4];
    const float* ln2b = (const float*)d_in[5];
    const float* wq   = (const float*)d_in[6];
    const float* bq   = (const float*)d_in[7];
    const float* wk   = (const float*)d_in[8];
    const float* bk   = (const float*)d_in[9];
    const float* wv   = (const float*)d_in[10];
    const float* bv   = (const float*)d_in[11];
    const float* wo   = (const float*)d_in[12];
    const float* bo   = (const float*)d_in[13];
    const float* w1   = (const float*)d_in[14];
    const float* b1   = (const float*)d_in[15];
    const float* w2   = (const float*)d_in[16];
    const float* b2   = (const float*)d_in[17];

    char* ws = (char*)d_ws;
    const size_t MB = 1024 * 1024;
    ushort* WQT = (ushort*)(ws + 0 * MB);
    ushort* WKT = (ushort*)(ws + 2 * MB);
    ushort* WVT = (ushort*)(ws + 4 * MB);
    ushort* WOT = (ushort*)(ws + 6 * MB);
    ushort* W1T = (ushort*)(ws + 8 * MB);    // [4096][1024]
    ushort* W2T = (ushort*)(ws + 16 * MB);   // [1024][4096]
    ushort* H1  = (ushort*)(ws + 24 * MB);   // [8192][1024], reused as CTX
    ushort* CTX = H1;
    ushort* Qb  = (ushort*)(ws + 40 * MB);   // [128][1024][64], reused as H2
    ushort* H2  = Qb;
    ushort* Kb  = (ushort*)(ws + 56 * MB);
    ushort* Vb  = (ushort*)(ws + 72 * MB);
    ushort* FF1 = (ushort*)(ws + 56 * MB);   // [8192][4096] overlays dead K,V

    float* xout = (float*)d_out;             // x2 lives here, then final out

    const dim3 tb(32, 8);
    transp_kernel<<<dim3(32, 32), tb, 0, stream>>>(wq, WQT, 1024, 1024);
    transp_kernel<<<dim3(32, 32), tb, 0, stream>>>(wk, WKT, 1024, 1024);
    transp_kernel<<<dim3(32, 32), tb, 0, stream>>>(wv, WVT, 1024, 1024);
    transp_kernel<<<dim3(32, 32), tb, 0, stream>>>(wo, WOT, 1024, 1024);
    transp_kernel<<<dim3(128, 32), tb, 0, stream>>>(w1, W1T, 1024, 4096);
    transp_kernel<<<dim3(32, 128), tb, 0, stream>>>(w2, W2T, 4096, 1024);

    ln_kernel<<<8192, 256, 0, stream>>>(x, ln1w, ln1b, H1);

    gemm_bt<1><<<dim3(8, 64), 256, 0, stream>>>(H1, WQT, bq, Qb, nullptr, 8192, 1024, 1024);
    gemm_bt<1><<<dim3(8, 64), 256, 0, stream>>>(H1, WKT, bk, Kb, nullptr, 8192, 1024, 1024);
    gemm_bt<1><<<dim3(8, 64), 256, 0, stream>>>(H1, WVT, bv, Vb, nullptr, 8192, 1024, 1024);

    attn_kernel<<<2048, 256, 0, stream>>>(Qb, Kb, Vb, CTX);

    gemm_bt<2><<<dim3(8, 64), 256, 0, stream>>>(CTX, WOT, bo, xout, x, 8192, 1024, 1024);

    ln_kernel<<<8192, 256, 0, stream>>>(xout, ln2w, ln2b, H2);

    gemm_bt<3><<<dim3(32, 64), 256, 0, stream>>>(H2, W1T, b1, FF1, nullptr, 8192, 4096, 1024);

    gemm_bt<2><<<dim3(8, 64), 256, 0, stream>>>(FF1, W2T, b2, xout, xout, 8192, 1024, 4096);

    (void)in_sizes; (void)n_in; (void)out_size; (void)ws_size;
}

// Round 2
// 640.216 us; speedup vs baseline: 1.0343x; 1.0343x over previous
//
#include <hip/hip_runtime.h>
#include <hip/hip_bf16.h>
#include <math.h>

// ---------------------------------------------------------------------------
// TransformerBlock: B=8 T=1024 C=1024 H=16 d=64, bf16 MFMA compute, fp32 acc.
// R2: global_load_lds(16B) GEMM staging with XOR swizzle; fused QKV GEMM;
//     barrier-free attention with V^T global layout + paired q-tiles.
// ---------------------------------------------------------------------------

#define DEVI __device__ __forceinline__

typedef __attribute__((ext_vector_type(4))) float floatx4;
typedef __attribute__((ext_vector_type(8))) short shortx8;   // 8 bf16 = 4 VGPRs

DEVI ushort f2b(float f) {
    __hip_bfloat16 h = __float2bfloat16(f);
    return __builtin_bit_cast(ushort, h);
}

DEVI void gl_lds16(const ushort* g, ushort* l) {
    // 16B direct global->LDS. LDS dest = wave-uniform base + lane*16.
    __builtin_amdgcn_global_load_lds(
        (const __attribute__((address_space(1))) void*)g,
        (__attribute__((address_space(3))) void*)l, 16, 0, 0);
}

// ---------------------------------------------------------------------------
// Weight transpose + fp32->bf16 cast: src[R][C] fp32  ->  dst[C][R] bf16
// ---------------------------------------------------------------------------
__global__ void transp_kernel(const float* __restrict__ src,
                              ushort* __restrict__ dst, int R, int C) {
    __shared__ float tile[32][33];
    const int c0 = blockIdx.x * 32, r0 = blockIdx.y * 32;
    const int tx = threadIdx.x, ty = threadIdx.y;   // 32 x 8
#pragma unroll
    for (int i = 0; i < 32; i += 8)
        tile[ty + i][tx] = src[(size_t)(r0 + ty + i) * C + c0 + tx];
    __syncthreads();
#pragma unroll
    for (int i = 0; i < 32; i += 8)
        dst[(size_t)(c0 + ty + i) * R + r0 + tx] = f2b(tile[tx][ty + i]);
}

// ---------------------------------------------------------------------------
// LayerNorm over C=1024, one block (256 thr) per token. fp32 in, bf16 out.
// ---------------------------------------------------------------------------
__global__ __launch_bounds__(256)
void ln_kernel(const float* __restrict__ x, const float* __restrict__ w,
               const float* __restrict__ b, ushort* __restrict__ out) {
    __shared__ float red[8];
    const int m = blockIdx.x;
    const int tid = threadIdx.x;
    const float4 xv = *(const float4*)&x[(size_t)m * 1024 + tid * 4];
    float s  = xv.x + xv.y + xv.z + xv.w;
    float s2 = xv.x * xv.x + xv.y * xv.y + xv.z * xv.z + xv.w * xv.w;
#pragma unroll
    for (int o = 32; o >= 1; o >>= 1) {
        s  += __shfl_xor(s, o, 64);
        s2 += __shfl_xor(s2, o, 64);
    }
    const int wv_ = tid >> 6;
    if ((tid & 63) == 0) { red[wv_] = s; red[4 + wv_] = s2; }
    __syncthreads();
    s  = red[0] + red[1] + red[2] + red[3];
    s2 = red[4] + red[5] + red[6] + red[7];
    const float mu   = s * (1.0f / 1024.0f);
    const float var  = s2 * (1.0f / 1024.0f) - mu * mu;
    const float rstd = rsqrtf(var + 1e-5f);
    const float4 wv = *(const float4*)&w[tid * 4];
    const float4 bv = *(const float4*)&b[tid * 4];
    ushort o4[4];
    o4[0] = f2b((xv.x - mu) * rstd * wv.x + bv.x);
    o4[1] = f2b((xv.y - mu) * rstd * wv.y + bv.y);
    o4[2] = f2b((xv.z - mu) * rstd * wv.z + bv.z);
    o4[3] = f2b((xv.w - mu) * rstd * wv.w + bv.w);
    *(uint2*)&out[(size_t)m * 1024 + tid * 4] = *(uint2*)o4;
}

// ---------------------------------------------------------------------------
// GEMM: C[M][N] = A[M][K] @ Bt[N][K]^T (+bias, epilogue variants)
//   MODE 1: fused QKV: gn<1024 -> Q[B][H][T][d]; <2048 -> K same; else
//           V^T[B][H][d][T]  (all bf16)
//   MODE 2: fp32 out = resid + acc + bias
//   MODE 3: bf16 out = gelu(acc + bias)
// 128x128 tile, BK=64, 4 waves x (64x64 via 4x4 16x16x32 MFMA).
// Staging: global_load_lds 16B, unpadded 64-elem LDS rows, XOR-16B source
// swizzle (LDS[r][cb] = G[r][cb^(r&7)]) so frag ds_read_b128 is conflict-free.
// ---------------------------------------------------------------------------
template <int MODE>
__global__ __launch_bounds__(256)
void gemm_bt(const ushort* __restrict__ A, const ushort* __restrict__ Bt,
             const float* __restrict__ bias, void* __restrict__ out,
             const float* __restrict__ resid, int M, int N, int K,
             void* __restrict__ out2, void* __restrict__ out3) {
    __shared__ ushort sA[128 * 64];
    __shared__ ushort sB[128 * 64];
    const int tid  = threadIdx.x;
    const int lane = tid & 63;
    const int wave = tid >> 6;
    const int quad = lane >> 4;
    const int l15  = lane & 15;
    const int wm   = (wave & 1) * 64;
    const int wn   = (wave >> 1) * 64;
    const int m0   = blockIdx.y * 128;
    const int n0   = blockIdx.x * 128;

    floatx4 acc[4][4] = {};

    const int lrow = lane >> 3;       // 0..7 row within an 8-row chunk
    const int scb  = (lane & 7) ^ lrow;  // swizzled SOURCE col-block
    const ushort* Ag = A  + (size_t)(m0 + wave * 8 + lrow) * K + scb * 8;
    const ushort* Bg = Bt + (size_t)(n0 + wave * 8 + lrow) * K + scb * 8;

    for (int k0 = 0; k0 < K; k0 += 64) {
        __syncthreads();   // WAR: previous reads done before overwrite
#pragma unroll
        for (int p = 0; p < 4; ++p) {
            gl_lds16(Ag + (size_t)(p * 32) * K + k0, sA + (p * 32 + wave * 8) * 64);
            gl_lds16(Bg + (size_t)(p * 32) * K + k0, sB + (p * 32 + wave * 8) * 64);
        }
        __syncthreads();   // drains vmcnt (global_load_lds) per barrier semantics
#pragma unroll
        for (int ks = 0; ks < 2; ++ks) {
            shortx8 af[4], bf[4];
#pragma unroll
            for (int i = 0; i < 4; ++i) {
                const int r = wm + i * 16 + l15;
                const int c = (ks * 4 + quad) ^ (r & 7);
                af[i] = *(const shortx8*)&sA[r * 64 + c * 8];
            }
#pragma unroll
            for (int j = 0; j < 4; ++j) {
                const int r = wn + j * 16 + l15;
                const int c = (ks * 4 + quad) ^ (r & 7);
                bf[j] = *(const shortx8*)&sB[r * 64 + c * 8];
            }
#pragma unroll
            for (int i = 0; i < 4; ++i)
#pragma unroll
                for (int j = 0; j < 4; ++j)
                    acc[i][j] = __builtin_amdgcn_mfma_f32_16x16x32_bf16(
                        af[i], bf[j], acc[i][j], 0, 0, 0);
        }
    }
    // epilogue: lane holds C[row=quad*4+r][col=l15] per 16x16 sub-tile
#pragma unroll
    for (int i = 0; i < 4; ++i) {
#pragma unroll
        for (int j = 0; j < 4; ++j) {
#pragma unroll
            for (int r = 0; r < 4; ++r) {
                const int gm = m0 + wm + i * 16 + quad * 4 + r;
                const int gn = n0 + wn + j * 16 + l15;
                float v = acc[i][j][r] + bias[gn];
                if constexpr (MODE == 1) {
                    const int mat = gn >> 10;       // uniform per block (128|1024)
                    const int cn  = gn & 1023;
                    const int h = cn >> 6, dd = cn & 63;
                    const int bb = gm >> 10, t = gm & 1023;
                    const size_t bh = (size_t)(bb * 16 + h);
                    const ushort val = f2b(v);
                    if (mat == 0)
                        ((ushort*)out )[(bh * 1024 + t) * 64 + dd] = val;
                    else if (mat == 1)
                        ((ushort*)out2)[(bh * 1024 + t) * 64 + dd] = val;
                    else
                        ((ushort*)out3)[(bh * 64 + dd) * 1024 + t] = val;
                } else if constexpr (MODE == 2) {
                    v += resid[(size_t)gm * N + gn];
                    ((float*)out)[(size_t)gm * N + gn] = v;
                } else if constexpr (MODE == 3) {
                    const float g = 0.5f * v * (1.0f + erff(v * 0.70710678f));
                    ((ushort*)out)[(size_t)gm * N + gn] = f2b(g);
                }
            }
        }
    }
}

// ---------------------------------------------------------------------------
// Flash-style causal attention, barrier-free.
// Q,K: [B*H][T][64] bf16; Vt: [B*H][64][T] bf16 (pre-transposed).
// Block = (bh, pair); processes q-tiles pr and 15-pr -> uniform 17 kv-iters.
// 4 waves x 16 q-rows; kv-tile 64. K/V fragments read DIRECTLY from global
// (both coalesced 16B loads); LDS only for per-wave P C->A layout transform.
// ---------------------------------------------------------------------------
__global__ __launch_bounds__(256)
void attn_kernel(const ushort* __restrict__ Q, const ushort* __restrict__ Kk,
                 const ushort* __restrict__ Vt, ushort* __restrict__ ctx) {
    __shared__ ushort sP[4][16 * 72];

    const int tid  = threadIdx.x;
    const int lane = tid & 63;
    const int wave = tid >> 6;
    const int quad = lane >> 4;
    const int l15  = lane & 15;

    const int pr = blockIdx.x & 7;       // pair index 0..7
    const int bh = blockIdx.x >> 3;      // 0..127
    const size_t base = (size_t)bh << 16;          // bh*1024*64
    const int bb = bh >> 4, h = bh & 15;

#pragma unroll
    for (int half = 0; half < 2; ++half) {
        const int qb = half ? (15 - pr) : pr;
        const int qrow = qb * 64 + wave * 16 + l15;
        const shortx8 qf0 = *(const shortx8*)&Q[base + (size_t)qrow * 64 + quad * 8];
        const shortx8 qf1 = *(const shortx8*)&Q[base + (size_t)qrow * 64 + 32 + quad * 8];

        float mstate[4], lstate[4];
        floatx4 oacc[4] = {};
#pragma unroll
        for (int r = 0; r < 4; ++r) { mstate[r] = -__builtin_inff(); lstate[r] = 0.0f; }

        for (int kt = 0; kt <= qb; ++kt) {
            // ---- S = Q @ K^T (16 x 64 per wave), K frags straight from global
            floatx4 s[4];
#pragma unroll
            for (int nt = 0; nt < 4; ++nt) {
                const size_t kr = base + (size_t)(kt * 64 + nt * 16 + l15) * 64;
                const shortx8 kf0 = *(const shortx8*)&Kk[kr + quad * 8];
                const shortx8 kf1 = *(const shortx8*)&Kk[kr + 32 + quad * 8];
                floatx4 z = {};
                z = __builtin_amdgcn_mfma_f32_16x16x32_bf16(qf0, kf0, z, 0, 0, 0);
                z = __builtin_amdgcn_mfma_f32_16x16x32_bf16(qf1, kf1, z, 0, 0, 0);
                s[nt] = z;
            }
            // ---- scale + causal mask (diagonal tile only)
#pragma unroll
            for (int nt = 0; nt < 4; ++nt)
#pragma unroll
                for (int r = 0; r < 4; ++r) {
                    float sv = s[nt][r] * 0.125f;
                    if (kt == qb) {
                        const int col = nt * 16 + l15;
                        const int row = wave * 16 + quad * 4 + r;
                        if (col > row) sv = -__builtin_inff();
                    }
                    s[nt][r] = sv;
                }
            // ---- online softmax (rows live across the 16 lanes of a quad)
            float mnew[4], alpha[4];
#pragma unroll
            for (int r = 0; r < 4; ++r) {
                float mt = fmaxf(fmaxf(s[0][r], s[1][r]), fmaxf(s[2][r], s[3][r]));
#pragma unroll
                for (int o = 8; o >= 1; o >>= 1) mt = fmaxf(mt, __shfl_xor(mt, o, 64));
                mnew[r]  = fmaxf(mstate[r], mt);
                alpha[r] = __expf(mstate[r] - mnew[r]);
                mstate[r] = mnew[r];
            }
#pragma unroll
            for (int r = 0; r < 4; ++r) {
                float rs = 0.0f;
#pragma unroll
                for (int nt = 0; nt < 4; ++nt) {
                    const float p = __expf(s[nt][r] - mnew[r]);
                    s[nt][r] = p;
                    rs += p;
                }
#pragma unroll
                for (int o = 8; o >= 1; o >>= 1) rs += __shfl_xor(rs, o, 64);
                lstate[r] = alpha[r] * lstate[r] + rs;
#pragma unroll
                for (int dt = 0; dt < 4; ++dt) oacc[dt][r] *= alpha[r];
            }
            // ---- P: C-layout -> per-wave LDS -> A-layout (no cross-wave sync)
#pragma unroll
            for (int nt = 0; nt < 4; ++nt)
#pragma unroll
                for (int r = 0; r < 4; ++r)
                    sP[wave][(quad * 4 + r) * 72 + nt * 16 + l15] = f2b(s[nt][r]);
            __asm__ volatile("s_waitcnt lgkmcnt(0)" ::: "memory");
            const shortx8 pf0 = *(const shortx8*)&sP[wave][l15 * 72 + quad * 8];
            const shortx8 pf1 = *(const shortx8*)&sP[wave][l15 * 72 + 32 + quad * 8];
            // ---- O += P @ V, V^T frags straight from global
#pragma unroll
            for (int dt = 0; dt < 4; ++dt) {
                const size_t vr = base + (size_t)(dt * 16 + l15) * 1024 + kt * 64;
                const shortx8 v0 = *(const shortx8*)&Vt[vr + quad * 8];
                const shortx8 v1 = *(const shortx8*)&Vt[vr + 32 + quad * 8];
                oacc[dt] = __builtin_amdgcn_mfma_f32_16x16x32_bf16(pf0, v0, oacc[dt], 0, 0, 0);
                oacc[dt] = __builtin_amdgcn_mfma_f32_16x16x32_bf16(pf1, v1, oacc[dt], 0, 0, 0);
            }
        }
        // ---- normalize, write ctx [B][T][C]
#pragma unroll
        for (int dt = 0; dt < 4; ++dt)
#pragma unroll
            for (int r = 0; r < 4; ++r) {
                const int t = qb * 64 + wave * 16 + quad * 4 + r;
                const int dim = dt * 16 + l15;
                const float v = oacc[dt][r] / lstate[r];
                ctx[(size_t)(bb * 1024 + t) * 1024 + h * 64 + dim] = f2b(v);
            }
    }
}

// ---------------------------------------------------------------------------
// Launch
// ---------------------------------------------------------------------------
extern "C" void kernel_launch(void* const* d_in, const int* in_sizes, int n_in,
                              void* d_out, int out_size, void* d_ws, size_t ws_size,
                              hipStream_t stream) {
    const float* x    = (const float*)d_in[0];
    const float* ln1w = (const float*)d_in[2];
    const float* ln1b = (const float*)d_in[3];
    const float* ln2w = (const float*)d_in[4];
    const float* ln2b = (const float*)d_in[5];
    const float* wq   = (const float*)d_in[6];
    const float* bq   = (const float*)d_in[7];
    const float* wk   = (const float*)d_in[8];
    const float* bk   = (const float*)d_in[9];
    const float* wv   = (const float*)d_in[10];
    const float* bv   = (const float*)d_in[11];
    const float* wo   = (const float*)d_in[12];
    const float* bo   = (const float*)d_in[13];
    const float* w1   = (const float*)d_in[14];
    const float* b1   = (const float*)d_in[15];
    const float* w2   = (const float*)d_in[16];
    const float* b2   = (const float*)d_in[17];

    char* ws = (char*)d_ws;
    const size_t MB = 1024 * 1024;
    ushort* WQKVT = (ushort*)(ws + 0 * MB);     // [3072][1024] bf16 (wq|wk|wv ^T)
    ushort* WOT   = (ushort*)(ws + 6 * MB);     // [1024][1024]
    ushort* W1T   = (ushort*)(ws + 8 * MB);     // [4096][1024]
    ushort* W2T   = (ushort*)(ws + 16 * MB);    // [1024][4096]
    ushort* H1    = (ushort*)(ws + 24 * MB);    // [8192][1024]; H2 overlays later
    ushort* H2    = H1;
    ushort* Qb    = (ushort*)(ws + 40 * MB);    // [128][1024][64]
    ushort* Kb    = (ushort*)(ws + 56 * MB);    // [128][1024][64]
    ushort* Vbt   = (ushort*)(ws + 72 * MB);    // [128][64][1024]
    ushort* FF1   = (ushort*)(ws + 40 * MB);    // [8192][4096] overlays Q,K,V (dead)
    ushort* CTX   = (ushort*)(ws + 104 * MB);   // [8192][1024]

    float* xout = (float*)d_out;                // x2 lives here, then final out

    // bias QKV concat: bq|bk|bv are separate — gemm reads bias[gn]; build a
    // concatenated view is not possible without a copy; instead we exploit
    // that MODE 1 blocks are mat-uniform and pass per-matrix bias via bias+gn
    // arithmetic: simplest is a tiny concat copy into ws.
    float* bqkv = (float*)(ws + 120 * MB);      // 3072 floats = 12 KB
    hipMemcpyAsync(bqkv,        bq, 1024 * 4, hipMemcpyDeviceToDevice, stream);
    hipMemcpyAsync(bqkv + 1024, bk, 1024 * 4, hipMemcpyDeviceToDevice, stream);
    hipMemcpyAsync(bqkv + 2048, bv, 1024 * 4, hipMemcpyDeviceToDevice, stream);

    const dim3 tb(32, 8);
    transp_kernel<<<dim3(32, 32), tb, 0, stream>>>(wq, WQKVT, 1024, 1024);
    transp_kernel<<<dim3(32, 32), tb, 0, stream>>>(wk, WQKVT + 1024 * 1024, 1024, 1024);
    transp_kernel<<<dim3(32, 32), tb, 0, stream>>>(wv, WQKVT + 2048 * 1024, 1024, 1024);
    transp_kernel<<<dim3(32, 32), tb, 0, stream>>>(wo, WOT, 1024, 1024);
    transp_kernel<<<dim3(128, 32), tb, 0, stream>>>(w1, W1T, 1024, 4096);
    transp_kernel<<<dim3(32, 128), tb, 0, stream>>>(w2, W2T, 4096, 1024);

    ln_kernel<<<8192, 256, 0, stream>>>(x, ln1w, ln1b, H1);

    gemm_bt<1><<<dim3(24, 64), 256, 0, stream>>>(H1, WQKVT, bqkv, Qb, nullptr,
                                                 8192, 3072, 1024, Kb, Vbt);

    attn_kernel<<<1024, 256, 0, stream>>>(Qb, Kb, Vbt, CTX);

    gemm_bt<2><<<dim3(8, 64), 256, 0, stream>>>(CTX, WOT, bo, xout, x,
                                                8192, 1024, 1024, nullptr, nullptr);

    ln_kernel<<<8192, 256, 0, stream>>>(xout, ln2w, ln2b, H2);

    gemm_bt<3><<<dim3(32, 64), 256, 0, stream>>>(H2, W1T, b1, FF1, nullptr,
                                                 8192, 4096, 1024, nullptr, nullptr);

    gemm_bt<2><<<dim3(8, 64), 256, 0, stream>>>(FF1, W2T, b2, xout, xout,
                                                8192, 1024, 4096, nullptr, nullptr);

    (void)in_sizes; (void)n_in; (void)out_size; (void)ws_size;
}

// Round 3
// 543.766 us; speedup vs baseline: 1.2178x; 1.1774x over previous
//
#include <hip/hip_runtime.h>
#include <hip/hip_bf16.h>
#include <math.h>

// ---------------------------------------------------------------------------
// TransformerBlock: B=8 T=1024 C=1024 H=16 d=64, bf16 MFMA compute, fp32 acc.
// R3: attention restructured — K/V staged to LDS via global_load_lds(16B)
//     with XOR swizzle, one block per (bh,qb) descending, exp2-domain softmax.
// ---------------------------------------------------------------------------

#define DEVI __device__ __forceinline__

typedef __attribute__((ext_vector_type(4))) float floatx4;
typedef __attribute__((ext_vector_type(8))) short shortx8;   // 8 bf16 = 4 VGPRs

DEVI ushort f2b(float f) {
    __hip_bfloat16 h = __float2bfloat16(f);
    return __builtin_bit_cast(ushort, h);
}

DEVI void gl_lds16(const ushort* g, ushort* l) {
    // 16B direct global->LDS. LDS dest = wave-uniform base + lane*16.
    __builtin_amdgcn_global_load_lds(
        (const __attribute__((address_space(1))) void*)g,
        (__attribute__((address_space(3))) void*)l, 16, 0, 0);
}

// ---------------------------------------------------------------------------
// Weight transpose + fp32->bf16 cast: src[R][C] fp32  ->  dst[C][R] bf16
// ---------------------------------------------------------------------------
__global__ void transp_kernel(const float* __restrict__ src,
                              ushort* __restrict__ dst, int R, int C) {
    __shared__ float tile[32][33];
    const int c0 = blockIdx.x * 32, r0 = blockIdx.y * 32;
    const int tx = threadIdx.x, ty = threadIdx.y;   // 32 x 8
#pragma unroll
    for (int i = 0; i < 32; i += 8)
        tile[ty + i][tx] = src[(size_t)(r0 + ty + i) * C + c0 + tx];
    __syncthreads();
#pragma unroll
    for (int i = 0; i < 32; i += 8)
        dst[(size_t)(c0 + ty + i) * R + r0 + tx] = f2b(tile[tx][ty + i]);
}

// ---------------------------------------------------------------------------
// LayerNorm over C=1024, one block (256 thr) per token. fp32 in, bf16 out.
// ---------------------------------------------------------------------------
__global__ __launch_bounds__(256)
void ln_kernel(const float* __restrict__ x, const float* __restrict__ w,
               const float* __restrict__ b, ushort* __restrict__ out) {
    __shared__ float red[8];
    const int m = blockIdx.x;
    const int tid = threadIdx.x;
    const float4 xv = *(const float4*)&x[(size_t)m * 1024 + tid * 4];
    float s  = xv.x + xv.y + xv.z + xv.w;
    float s2 = xv.x * xv.x + xv.y * xv.y + xv.z * xv.z + xv.w * xv.w;
#pragma unroll
    for (int o = 32; o >= 1; o >>= 1) {
        s  += __shfl_xor(s, o, 64);
        s2 += __shfl_xor(s2, o, 64);
    }
    const int wv_ = tid >> 6;
    if ((tid & 63) == 0) { red[wv_] = s; red[4 + wv_] = s2; }
    __syncthreads();
    s  = red[0] + red[1] + red[2] + red[3];
    s2 = red[4] + red[5] + red[6] + red[7];
    const float mu   = s * (1.0f / 1024.0f);
    const float var  = s2 * (1.0f / 1024.0f) - mu * mu;
    const float rstd = rsqrtf(var + 1e-5f);
    const float4 wv = *(const float4*)&w[tid * 4];
    const float4 bv = *(const float4*)&b[tid * 4];
    ushort o4[4];
    o4[0] = f2b((xv.x - mu) * rstd * wv.x + bv.x);
    o4[1] = f2b((xv.y - mu) * rstd * wv.y + bv.y);
    o4[2] = f2b((xv.z - mu) * rstd * wv.z + bv.z);
    o4[3] = f2b((xv.w - mu) * rstd * wv.w + bv.w);
    *(uint2*)&out[(size_t)m * 1024 + tid * 4] = *(uint2*)o4;
}

// ---------------------------------------------------------------------------
// GEMM: C[M][N] = A[M][K] @ Bt[N][K]^T (+bias, epilogue variants)
//   MODE 1: fused QKV: gn<1024 -> Q[B][H][T][d]; <2048 -> K same; else
//           V^T[B][H][d][T]  (all bf16)
//   MODE 2: fp32 out = resid + acc + bias
//   MODE 3: bf16 out = gelu(acc + bias)
// 128x128 tile, BK=64, 4 waves x (64x64 via 4x4 16x16x32 MFMA).
// Staging: global_load_lds 16B, unpadded 64-elem LDS rows, XOR-16B source
// swizzle (LDS[r][cb] = G[r][cb^(r&7)]) so frag ds_read_b128 is conflict-free.
// ---------------------------------------------------------------------------
template <int MODE>
__global__ __launch_bounds__(256)
void gemm_bt(const ushort* __restrict__ A, const ushort* __restrict__ Bt,
             const float* __restrict__ bias, void* __restrict__ out,
             const float* __restrict__ resid, int M, int N, int K,
             void* __restrict__ out2, void* __restrict__ out3) {
    __shared__ ushort sA[128 * 64];
    __shared__ ushort sB[128 * 64];
    const int tid  = threadIdx.x;
    const int lane = tid & 63;
    const int wave = tid >> 6;
    const int quad = lane >> 4;
    const int l15  = lane & 15;
    const int wm   = (wave & 1) * 64;
    const int wn   = (wave >> 1) * 64;
    const int m0   = blockIdx.y * 128;
    const int n0   = blockIdx.x * 128;

    floatx4 acc[4][4] = {};

    const int lrow = lane >> 3;       // 0..7 row within an 8-row chunk
    const int scb  = (lane & 7) ^ lrow;  // swizzled SOURCE col-block
    const ushort* Ag = A  + (size_t)(m0 + wave * 8 + lrow) * K + scb * 8;
    const ushort* Bg = Bt + (size_t)(n0 + wave * 8 + lrow) * K + scb * 8;

    for (int k0 = 0; k0 < K; k0 += 64) {
        __syncthreads();   // WAR: previous reads done before overwrite
#pragma unroll
        for (int p = 0; p < 4; ++p) {
            gl_lds16(Ag + (size_t)(p * 32) * K + k0, sA + (p * 32 + wave * 8) * 64);
            gl_lds16(Bg + (size_t)(p * 32) * K + k0, sB + (p * 32 + wave * 8) * 64);
        }
        __syncthreads();   // drains vmcnt (global_load_lds) per barrier semantics
#pragma unroll
        for (int ks = 0; ks < 2; ++ks) {
            shortx8 af[4], bf[4];
#pragma unroll
            for (int i = 0; i < 4; ++i) {
                const int r = wm + i * 16 + l15;
                const int c = (ks * 4 + quad) ^ (r & 7);
                af[i] = *(const shortx8*)&sA[r * 64 + c * 8];
            }
#pragma unroll
            for (int j = 0; j < 4; ++j) {
                const int r = wn + j * 16 + l15;
                const int c = (ks * 4 + quad) ^ (r & 7);
                bf[j] = *(const shortx8*)&sB[r * 64 + c * 8];
            }
#pragma unroll
            for (int i = 0; i < 4; ++i)
#pragma unroll
                for (int j = 0; j < 4; ++j)
                    acc[i][j] = __builtin_amdgcn_mfma_f32_16x16x32_bf16(
                        af[i], bf[j], acc[i][j], 0, 0, 0);
        }
    }
    // epilogue: lane holds C[row=quad*4+r][col=l15] per 16x16 sub-tile
#pragma unroll
    for (int i = 0; i < 4; ++i) {
#pragma unroll
        for (int j = 0; j < 4; ++j) {
#pragma unroll
            for (int r = 0; r < 4; ++r) {
                const int gm = m0 + wm + i * 16 + quad * 4 + r;
                const int gn = n0 + wn + j * 16 + l15;
                float v = acc[i][j][r] + bias[gn];
                if constexpr (MODE == 1) {
                    const int mat = gn >> 10;       // uniform per block (128|1024)
                    const int cn  = gn & 1023;
                    const int h = cn >> 6, dd = cn & 63;
                    const int bb = gm >> 10, t = gm & 1023;
                    const size_t bh = (size_t)(bb * 16 + h);
                    const ushort val = f2b(v);
                    if (mat == 0)
                        ((ushort*)out )[(bh * 1024 + t) * 64 + dd] = val;
                    else if (mat == 1)
                        ((ushort*)out2)[(bh * 1024 + t) * 64 + dd] = val;
                    else
                        ((ushort*)out3)[(bh * 64 + dd) * 1024 + t] = val;
                } else if constexpr (MODE == 2) {
                    v += resid[(size_t)gm * N + gn];
                    ((float*)out)[(size_t)gm * N + gn] = v;
                } else if constexpr (MODE == 3) {
                    const float g = 0.5f * v * (1.0f + erff(v * 0.70710678f));
                    ((ushort*)out)[(size_t)gm * N + gn] = f2b(g);
                }
            }
        }
    }
}

// ---------------------------------------------------------------------------
// Flash-style causal attention, LDS-staged.
// Q,K: [B*H][T][64] bf16; Vt: [B*H][64][T] bf16 (pre-transposed).
// Block = (qb_desc, bh): one 64-row q-tile, kv-tiles of 64 staged to LDS via
// global_load_lds(16B) + XOR swizzle (same pattern as gemm_bt). 2048 blocks,
// descending qb so the long blocks launch first. Softmax in exp2 domain.
// ---------------------------------------------------------------------------
__global__ __launch_bounds__(256)
void attn_kernel(const ushort* __restrict__ Q, const ushort* __restrict__ Kk,
                 const ushort* __restrict__ Vt, ushort* __restrict__ ctx) {
    __shared__ ushort sK[64 * 64];
    __shared__ ushort sV[64 * 64];     // V^T tile: [d][64 kv-cols]
    __shared__ ushort sP[4][16 * 72];

    const int tid  = threadIdx.x;
    const int lane = tid & 63;
    const int wave = tid >> 6;
    const int quad = lane >> 4;
    const int l15  = lane & 15;

    const int qb = 15 - (blockIdx.x >> 7);   // descending workload
    const int bh = blockIdx.x & 127;
    const size_t base = (size_t)bh << 16;    // bh*1024*64
    const int bb = bh >> 4, h = bh & 15;

    // staging lanes (same pattern as gemm_bt)
    const int lrow = lane >> 3;              // 0..7
    const int scb  = (lane & 7) ^ lrow;      // swizzled source col-block
    const ushort* Kg = Kk + base + (size_t)(wave * 8 + lrow) * 64 + scb * 8;
    const ushort* Vg = Vt + base + (size_t)(wave * 8 + lrow) * 1024 + scb * 8;

    // Q fragments (A-operand) for this wave's 16 rows
    const int qrow = qb * 64 + wave * 16 + l15;
    const shortx8 qf0 = *(const shortx8*)&Q[base + (size_t)qrow * 64 + quad * 8];
    const shortx8 qf1 = *(const shortx8*)&Q[base + (size_t)qrow * 64 + 32 + quad * 8];

    // softmax runs in exp2 domain: logits pre-scaled by 1/8 * log2(e)
    const float SC = 0.125f * 1.44269504f;

    float mstate[4], lstate[4];
    floatx4 oacc[4] = {};
#pragma unroll
    for (int r = 0; r < 4; ++r) { mstate[r] = -__builtin_inff(); lstate[r] = 0.0f; }

    for (int kt = 0; kt <= qb; ++kt) {
        __syncthreads();   // WAR on sK/sV
#pragma unroll
        for (int p = 0; p < 2; ++p) {
            gl_lds16(Kg + (size_t)kt * 4096 + (size_t)p * 2048,
                     sK + (p * 32 + wave * 8) * 64);
            gl_lds16(Vg + (size_t)kt * 64 + (size_t)p * 32 * 1024,
                     sV + (p * 32 + wave * 8) * 64);
        }
        __syncthreads();   // drain staging

        // ---- S = Q @ K^T (16 x 64 per wave) from LDS
        floatx4 s[4];
#pragma unroll
        for (int nt = 0; nt < 4; ++nt) {
            const int r = nt * 16 + l15;
            const int c0 = quad ^ (r & 7);
            const int c1 = (4 + quad) ^ (r & 7);
            const shortx8 kf0 = *(const shortx8*)&sK[r * 64 + c0 * 8];
            const shortx8 kf1 = *(const shortx8*)&sK[r * 64 + c1 * 8];
            floatx4 z = {};
            z = __builtin_amdgcn_mfma_f32_16x16x32_bf16(qf0, kf0, z, 0, 0, 0);
            z = __builtin_amdgcn_mfma_f32_16x16x32_bf16(qf1, kf1, z, 0, 0, 0);
            s[nt] = z;
        }
        // ---- scale (exp2 domain) + causal mask (diagonal tile only)
#pragma unroll
        for (int nt = 0; nt < 4; ++nt)
#pragma unroll
            for (int r = 0; r < 4; ++r) {
                float sv = s[nt][r] * SC;
                if (kt == qb) {
                    const int col = nt * 16 + l15;
                    const int row = wave * 16 + quad * 4 + r;
                    if (col > row) sv = -__builtin_inff();
                }
                s[nt][r] = sv;
            }
        // ---- online softmax (rows live across the 16 lanes of a quad)
        float mnew[4], alpha[4];
#pragma unroll
        for (int r = 0; r < 4; ++r) {
            float mt = fmaxf(fmaxf(s[0][r], s[1][r]), fmaxf(s[2][r], s[3][r]));
#pragma unroll
            for (int o = 8; o >= 1; o >>= 1) mt = fmaxf(mt, __shfl_xor(mt, o, 64));
            mnew[r]  = fmaxf(mstate[r], mt);
            alpha[r] = exp2f(mstate[r] - mnew[r]);
            mstate[r] = mnew[r];
        }
#pragma unroll
        for (int r = 0; r < 4; ++r) {
            float rs = 0.0f;
#pragma unroll
            for (int nt = 0; nt < 4; ++nt) {
                const float p = exp2f(s[nt][r] - mnew[r]);
                s[nt][r] = p;
                rs += p;
            }
#pragma unroll
            for (int o = 8; o >= 1; o >>= 1) rs += __shfl_xor(rs, o, 64);
            lstate[r] = alpha[r] * lstate[r] + rs;
#pragma unroll
            for (int dt = 0; dt < 4; ++dt) oacc[dt][r] *= alpha[r];
        }
        // ---- P: C-layout -> per-wave LDS -> A-layout (wave-local, no barrier)
#pragma unroll
        for (int nt = 0; nt < 4; ++nt)
#pragma unroll
            for (int r = 0; r < 4; ++r)
                sP[wave][(quad * 4 + r) * 72 + nt * 16 + l15] = f2b(s[nt][r]);
        __asm__ volatile("s_waitcnt lgkmcnt(0)" ::: "memory");
        const shortx8 pf0 = *(const shortx8*)&sP[wave][l15 * 72 + quad * 8];
        const shortx8 pf1 = *(const shortx8*)&sP[wave][l15 * 72 + 32 + quad * 8];
        // ---- O += P @ V from LDS (V^T rows = head dims)
#pragma unroll
        for (int dt = 0; dt < 4; ++dt) {
            const int r = dt * 16 + l15;
            const int c0 = quad ^ (r & 7);
            const int c1 = (4 + quad) ^ (r & 7);
            const shortx8 v0 = *(const shortx8*)&sV[r * 64 + c0 * 8];
            const shortx8 v1 = *(const shortx8*)&sV[r * 64 + c1 * 8];
            oacc[dt] = __builtin_amdgcn_mfma_f32_16x16x32_bf16(pf0, v0, oacc[dt], 0, 0, 0);
            oacc[dt] = __builtin_amdgcn_mfma_f32_16x16x32_bf16(pf1, v1, oacc[dt], 0, 0, 0);
        }
    }
    // ---- normalize, write ctx [B][T][C]
#pragma unroll
    for (int dt = 0; dt < 4; ++dt)
#pragma unroll
        for (int r = 0; r < 4; ++r) {
            const int t = qb * 64 + wave * 16 + quad * 4 + r;
            const int dim = dt * 16 + l15;
            const float v = oacc[dt][r] / lstate[r];
            ctx[(size_t)(bb * 1024 + t) * 1024 + h * 64 + dim] = f2b(v);
        }
}

// ---------------------------------------------------------------------------
// Launch
// ---------------------------------------------------------------------------
extern "C" void kernel_launch(void* const* d_in, const int* in_sizes, int n_in,
                              void* d_out, int out_size, void* d_ws, size_t ws_size,
                              hipStream_t stream) {
    const float* x    = (const float*)d_in[0];
    const float* ln1w = (const float*)d_in[2];
    const float* ln1b = (const float*)d_in[3];
    const float* ln2w = (const float*)d_in[4];
    const float* ln2b = (const float*)d_in[5];
    const float* wq   = (const float*)d_in[6];
    const float* bq   = (const float*)d_in[7];
    const float* wk   = (const float*)d_in[8];
    const float* bk   = (const float*)d_in[9];
    const float* wv   = (const float*)d_in[10];
    const float* bv   = (const float*)d_in[11];
    const float* wo   = (const float*)d_in[12];
    const float* bo   = (const float*)d_in[13];
    const float* w1   = (const float*)d_in[14];
    const float* b1   = (const float*)d_in[15];
    const float* w2   = (const float*)d_in[16];
    const float* b2   = (const float*)d_in[17];

    char* ws = (char*)d_ws;
    const size_t MB = 1024 * 1024;
    ushort* WQKVT = (ushort*)(ws + 0 * MB);     // [3072][1024] bf16 (wq|wk|wv ^T)
    ushort* WOT   = (ushort*)(ws + 6 * MB);     // [1024][1024]
    ushort* W1T   = (ushort*)(ws + 8 * MB);     // [4096][1024]
    ushort* W2T   = (ushort*)(ws + 16 * MB);    // [1024][4096]
    ushort* H1    = (ushort*)(ws + 24 * MB);    // [8192][1024]; H2 overlays later
    ushort* H2    = H1;
    ushort* Qb    = (ushort*)(ws + 40 * MB);    // [128][1024][64]
    ushort* Kb    = (ushort*)(ws + 56 * MB);    // [128][1024][64]
    ushort* Vbt   = (ushort*)(ws + 72 * MB);    // [128][64][1024]
    ushort* FF1   = (ushort*)(ws + 40 * MB);    // [8192][4096] overlays Q,K,V (dead)
    ushort* CTX   = (ushort*)(ws + 104 * MB);   // [8192][1024]

    float* xout = (float*)d_out;                // x2 lives here, then final out

    float* bqkv = (float*)(ws + 120 * MB);      // 3072 floats = 12 KB
    hipMemcpyAsync(bqkv,        bq, 1024 * 4, hipMemcpyDeviceToDevice, stream);
    hipMemcpyAsync(bqkv + 1024, bk, 1024 * 4, hipMemcpyDeviceToDevice, stream);
    hipMemcpyAsync(bqkv + 2048, bv, 1024 * 4, hipMemcpyDeviceToDevice, stream);

    const dim3 tb(32, 8);
    transp_kernel<<<dim3(32, 32), tb, 0, stream>>>(wq, WQKVT, 1024, 1024);
    transp_kernel<<<dim3(32, 32), tb, 0, stream>>>(wk, WQKVT + 1024 * 1024, 1024, 1024);
    transp_kernel<<<dim3(32, 32), tb, 0, stream>>>(wv, WQKVT + 2048 * 1024, 1024, 1024);
    transp_kernel<<<dim3(32, 32), tb, 0, stream>>>(wo, WOT, 1024, 1024);
    transp_kernel<<<dim3(128, 32), tb, 0, stream>>>(w1, W1T, 1024, 4096);
    transp_kernel<<<dim3(32, 128), tb, 0, stream>>>(w2, W2T, 4096, 1024);

    ln_kernel<<<8192, 256, 0, stream>>>(x, ln1w, ln1b, H1);

    gemm_bt<1><<<dim3(24, 64), 256, 0, stream>>>(H1, WQKVT, bqkv, Qb, nullptr,
                                                 8192, 3072, 1024, Kb, Vbt);

    attn_kernel<<<2048, 256, 0, stream>>>(Qb, Kb, Vbt, CTX);

    gemm_bt<2><<<dim3(8, 64), 256, 0, stream>>>(CTX, WOT, bo, xout, x,
                                                8192, 1024, 1024, nullptr, nullptr);

    ln_kernel<<<8192, 256, 0, stream>>>(xout, ln2w, ln2b, H2);

    gemm_bt<3><<<dim3(32, 64), 256, 0, stream>>>(H2, W1T, b1, FF1, nullptr,
                                                 8192, 4096, 1024, nullptr, nullptr);

    gemm_bt<2><<<dim3(8, 64), 256, 0, stream>>>(FF1, W2T, b2, xout, xout,
                                                8192, 1024, 4096, nullptr, nullptr);

    (void)in_sizes; (void)n_in; (void)out_size; (void)ws_size;
}

// Round 4
// 517.307 us; speedup vs baseline: 1.2801x; 1.0511x over previous
//
#include <hip/hip_runtime.h>
#include <hip/hip_bf16.h>
#include <math.h>

// ---------------------------------------------------------------------------
// TransformerBlock: B=8 T=1024 C=1024 H=16 d=64, bf16 MFMA compute, fp32 acc.
// R4: GEMM on mfma_32x32x16_bf16; V^T written via LDS transpose (coalesced);
//     tanh-GeLU epilogue; merged transposes; no bias memcpys.
// ---------------------------------------------------------------------------

#define DEVI __device__ __forceinline__

typedef __attribute__((ext_vector_type(4))) float floatx4;
typedef __attribute__((ext_vector_type(16))) float floatx16;
typedef __attribute__((ext_vector_type(8))) short shortx8;   // 8 bf16 = 4 VGPRs

DEVI ushort f2b(float f) {
    __hip_bfloat16 h = __float2bfloat16(f);
    return __builtin_bit_cast(ushort, h);
}

DEVI void gl_lds16(const ushort* g, ushort* l) {
    // 16B direct global->LDS. LDS dest = wave-uniform base + lane*16.
    __builtin_amdgcn_global_load_lds(
        (const __attribute__((address_space(1))) void*)g,
        (__attribute__((address_space(3))) void*)l, 16, 0, 0);
}

// tanh-form GeLU: max |err| vs exact erf-GeLU ~3e-3 — far under bf16 rounding
// at our output threshold. One exp2 + one divide instead of erff (~25 VALU).
DEVI float gelu_f(float v) {
    const float u0 = 0.7978845608f * v * (1.0f + 0.044715f * v * v);
    const float u  = fminf(fmaxf(u0, -15.0f), 15.0f);
    const float e  = exp2f(u * 2.885390082f);      // e^{2u}
    const float th = 1.0f - 2.0f / (e + 1.0f);     // tanh(u)
    return 0.5f * v * (1.0f + th);
}

// ---------------------------------------------------------------------------
// Fused transpose of the four 1024x1024 weights (z picks the matrix).
// src[R][C] fp32 -> dst[C][R] bf16.
// ---------------------------------------------------------------------------
__global__ void transp4_kernel(const float* __restrict__ s0, const float* __restrict__ s1,
                               const float* __restrict__ s2, const float* __restrict__ s3,
                               ushort* __restrict__ d0, ushort* __restrict__ d1,
                               ushort* __restrict__ d2, ushort* __restrict__ d3) {
    const int z = blockIdx.z;
    const float* src = (z == 0) ? s0 : (z == 1) ? s1 : (z == 2) ? s2 : s3;
    ushort*      dst = (z == 0) ? d0 : (z == 1) ? d1 : (z == 2) ? d2 : d3;
    __shared__ float tile[32][33];
    const int c0 = blockIdx.x * 32, r0 = blockIdx.y * 32;
    const int tx = threadIdx.x, ty = threadIdx.y;   // 32 x 8
#pragma unroll
    for (int i = 0; i < 32; i += 8)
        tile[ty + i][tx] = src[(size_t)(r0 + ty + i) * 1024 + c0 + tx];
    __syncthreads();
#pragma unroll
    for (int i = 0; i < 32; i += 8)
        dst[(size_t)(c0 + ty + i) * 1024 + r0 + tx] = f2b(tile[tx][ty + i]);
}

__global__ void transp_kernel(const float* __restrict__ src,
                              ushort* __restrict__ dst, int R, int C) {
    __shared__ float tile[32][33];
    const int c0 = blockIdx.x * 32, r0 = blockIdx.y * 32;
    const int tx = threadIdx.x, ty = threadIdx.y;   // 32 x 8
#pragma unroll
    for (int i = 0; i < 32; i += 8)
        tile[ty + i][tx] = src[(size_t)(r0 + ty + i) * C + c0 + tx];
    __syncthreads();
#pragma unroll
    for (int i = 0; i < 32; i += 8)
        dst[(size_t)(c0 + ty + i) * R + r0 + tx] = f2b(tile[tx][ty + i]);
}

// ---------------------------------------------------------------------------
// LayerNorm over C=1024, one block (256 thr) per token. fp32 in, bf16 out.
// ---------------------------------------------------------------------------
__global__ __launch_bounds__(256)
void ln_kernel(const float* __restrict__ x, const float* __restrict__ w,
               const float* __restrict__ b, ushort* __restrict__ out) {
    __shared__ float red[8];
    const int m = blockIdx.x;
    const int tid = threadIdx.x;
    const float4 xv = *(const float4*)&x[(size_t)m * 1024 + tid * 4];
    float s  = xv.x + xv.y + xv.z + xv.w;
    float s2 = xv.x * xv.x + xv.y * xv.y + xv.z * xv.z + xv.w * xv.w;
#pragma unroll
    for (int o = 32; o >= 1; o >>= 1) {
        s  += __shfl_xor(s, o, 64);
        s2 += __shfl_xor(s2, o, 64);
    }
    const int wv_ = tid >> 6;
    if ((tid & 63) == 0) { red[wv_] = s; red[4 + wv_] = s2; }
    __syncthreads();
    s  = red[0] + red[1] + red[2] + red[3];
    s2 = red[4] + red[5] + red[6] + red[7];
    const float mu   = s * (1.0f / 1024.0f);
    const float var  = s2 * (1.0f / 1024.0f) - mu * mu;
    const float rstd = rsqrtf(var + 1e-5f);
    const float4 wv = *(const float4*)&w[tid * 4];
    const float4 bv = *(const float4*)&b[tid * 4];
    ushort o4[4];
    o4[0] = f2b((xv.x - mu) * rstd * wv.x + bv.x);
    o4[1] = f2b((xv.y - mu) * rstd * wv.y + bv.y);
    o4[2] = f2b((xv.z - mu) * rstd * wv.z + bv.z);
    o4[3] = f2b((xv.w - mu) * rstd * wv.w + bv.w);
    *(uint2*)&out[(size_t)m * 1024 + tid * 4] = *(uint2*)o4;
}

// ---------------------------------------------------------------------------
// GEMM: C[M][N] = A[M][K] @ Bt[N][K]^T (+bias, epilogue variants)
//   MODE 1: fused QKV: mat0 -> Q[B][H][T][d]; mat1 -> K same;
//           mat2 -> V^T[B][H][d][T] via in-LDS transpose (coalesced stores)
//   MODE 2: fp32 out = resid + acc + bias
//   MODE 3: bf16 out = gelu(acc + bias)
// 128x128 tile, BK=64, 4 waves each 64x64 via 2x2 of mfma_32x32x16_bf16.
// Staging: global_load_lds 16B, unpadded 64-elem rows, XOR-16B swizzle
// (LDS[r][cb] = G[r][cb ^ (r&7)]) -> conflict-free ds_read_b128 fragments.
// A-frag (32x32x16): row=lane&31, k=(lane>>5)*8+j. C/D: col=lane&31,
// row=(reg&3)+8*(reg>>2)+4*(lane>>5)  [m74/m101-verified layout].
// ---------------------------------------------------------------------------
template <int MODE>
__global__ __launch_bounds__(256)
void gemm_bt(const ushort* __restrict__ A, const ushort* __restrict__ Bt,
             const float* __restrict__ biasQ, const float* __restrict__ biasK,
             const float* __restrict__ biasV,
             void* __restrict__ out, void* __restrict__ out2, void* __restrict__ out3,
             const float* __restrict__ resid, int M, int N, int K) {
    constexpr int LDSN = (MODE == 1) ? (128 * 144) : (128 * 64 * 2);
    __shared__ ushort lds[LDSN];
    ushort* sA = lds;
    ushort* sB = lds + 128 * 64;

    const int tid  = threadIdx.x;
    const int lane = tid & 63;
    const int wave = tid >> 6;
    const int l31  = lane & 31;
    const int half = lane >> 5;
    const int wm   = (wave & 1) * 64;
    const int wn   = (wave >> 1) * 64;
    const int m0   = blockIdx.y * 128;
    const int n0   = blockIdx.x * 128;

    floatx16 acc[2][2] = {};

    const int lrow = lane >> 3;          // 0..7
    const int scb  = (lane & 7) ^ lrow;  // swizzled SOURCE col-block
    const ushort* Ag = A  + (size_t)(m0 + wave * 8 + lrow) * K + scb * 8;
    const ushort* Bg = Bt + (size_t)(n0 + wave * 8 + lrow) * K + scb * 8;

    for (int k0 = 0; k0 < K; k0 += 64) {
        __syncthreads();   // WAR: previous reads done before overwrite
#pragma unroll
        for (int p = 0; p < 4; ++p) {
            gl_lds16(Ag + (size_t)(p * 32) * K + k0, sA + (p * 32 + wave * 8) * 64);
            gl_lds16(Bg + (size_t)(p * 32) * K + k0, sB + (p * 32 + wave * 8) * 64);
        }
        __syncthreads();   // barrier drains vmcnt (staging complete)
#pragma unroll
        for (int ks = 0; ks < 4; ++ks) {   // four K=16 steps
            const int cx = ks * 2 + half;  // 16B block holding this lane's k's
            shortx8 af[2], bf[2];
#pragma unroll
            for (int i = 0; i < 2; ++i) {
                const int r = wm + i * 32 + l31;
                af[i] = *(const shortx8*)&sA[r * 64 + (cx ^ (r & 7)) * 8];
            }
#pragma unroll
            for (int j = 0; j < 2; ++j) {
                const int r = wn + j * 32 + l31;
                bf[j] = *(const shortx8*)&sB[r * 64 + (cx ^ (r & 7)) * 8];
            }
#pragma unroll
            for (int i = 0; i < 2; ++i)
#pragma unroll
                for (int j = 0; j < 2; ++j)
                    acc[i][j] = __builtin_amdgcn_mfma_f32_32x32x16_bf16(
                        af[i], bf[j], acc[i][j], 0, 0, 0);
        }
    }

    if constexpr (MODE == 1) {
        const int mat = n0 >> 10;   // uniform per block
        if (mat < 2) {
            const float* bp = (mat == 0) ? biasQ : biasK;
            ushort* dst = (mat == 0) ? (ushort*)out : (ushort*)out2;
#pragma unroll
            for (int i = 0; i < 2; ++i)
#pragma unroll
                for (int j = 0; j < 2; ++j) {
                    const int cn = (n0 & 1023) + wn + j * 32 + l31;
                    const float bv = bp[cn];
                    const int h = cn >> 6, dd = cn & 63;
#pragma unroll
                    for (int reg = 0; reg < 16; ++reg) {
                        const int gm = m0 + wm + i * 32 + (reg & 3) + 8 * (reg >> 2) + 4 * half;
                        const int bb = gm >> 10, t = gm & 1023;
                        dst[((size_t)(bb * 16 + h) * 1024 + t) * 64 + dd] =
                            f2b(acc[i][j][reg] + bv);
                    }
                }
        } else {
            // V: bias + bf16 into LDS transposed, then coalesced V^T stores
            __syncthreads();           // all waves done reading sA/sB
            ushort* T = lds;           // [128][144]
#pragma unroll
            for (int i = 0; i < 2; ++i)
#pragma unroll
                for (int j = 0; j < 2; ++j) {
                    const int trow = wn + j * 32 + l31;            // V col (dim)
                    const float bv = biasV[(n0 & 1023) + trow];
#pragma unroll
                    for (int rq = 0; rq < 4; ++rq) {
                        const int tcol = wm + i * 32 + 8 * rq + 4 * half;  // t index
                        ushort pk[4];
#pragma unroll
                        for (int e = 0; e < 4; ++e)
                            pk[e] = f2b(acc[i][j][rq * 4 + e] + bv);
                        *(uint2*)&T[trow * 144 + tcol] = *(uint2*)pk;
                    }
                }
            __syncthreads();
            const int bb = m0 >> 10;
#pragma unroll
            for (int pass = 0; pass < 8; ++pass) {
                const int row = pass * 16 + (tid >> 4);     // dim-local 0..127
                const int cb  = (tid & 15) * 8;             // t-local, 8-elem chunks
                const uint4 val = *(const uint4*)&T[row * 144 + cb];
                const int dd = (n0 - 2048) + row;
                const int h = dd >> 6, dl = dd & 63;
                const int t = (m0 & 1023) + cb;
                *(uint4*)&((ushort*)out3)[((size_t)(bb * 16 + h) * 64 + dl) * 1024 + t] = val;
            }
        }
    } else {
#pragma unroll
        for (int i = 0; i < 2; ++i)
#pragma unroll
            for (int j = 0; j < 2; ++j) {
                const int gn = n0 + wn + j * 32 + l31;
                const float bv = biasQ[gn];
#pragma unroll
                for (int reg = 0; reg < 16; ++reg) {
                    const int gm = m0 + wm + i * 32 + (reg & 3) + 8 * (reg >> 2) + 4 * half;
                    float v = acc[i][j][reg] + bv;
                    if constexpr (MODE == 2) {
                        v += resid[(size_t)gm * N + gn];
                        ((float*)out)[(size_t)gm * N + gn] = v;
                    } else {
                        ((ushort*)out)[(size_t)gm * N + gn] = f2b(gelu_f(v));
                    }
                }
            }
    }
    (void)resid; (void)M;
}

// ---------------------------------------------------------------------------
// Flash-style causal attention, LDS-staged (unchanged from R3).
// ---------------------------------------------------------------------------
__global__ __launch_bounds__(256)
void attn_kernel(const ushort* __restrict__ Q, const ushort* __restrict__ Kk,
                 const ushort* __restrict__ Vt, ushort* __restrict__ ctx) {
    __shared__ ushort sK[64 * 64];
    __shared__ ushort sV[64 * 64];     // V^T tile: [d][64 kv-cols]
    __shared__ ushort sP[4][16 * 72];

    const int tid  = threadIdx.x;
    const int lane = tid & 63;
    const int wave = tid >> 6;
    const int quad = lane >> 4;
    const int l15  = lane & 15;

    const int qb = 15 - (blockIdx.x >> 7);   // descending workload
    const int bh = blockIdx.x & 127;
    const size_t base = (size_t)bh << 16;    // bh*1024*64
    const int bb = bh >> 4, h = bh & 15;

    const int lrow = lane >> 3;              // 0..7
    const int scb  = (lane & 7) ^ lrow;      // swizzled source col-block
    const ushort* Kg = Kk + base + (size_t)(wave * 8 + lrow) * 64 + scb * 8;
    const ushort* Vg = Vt + base + (size_t)(wave * 8 + lrow) * 1024 + scb * 8;

    const int qrow = qb * 64 + wave * 16 + l15;
    const shortx8 qf0 = *(const shortx8*)&Q[base + (size_t)qrow * 64 + quad * 8];
    const shortx8 qf1 = *(const shortx8*)&Q[base + (size_t)qrow * 64 + 32 + quad * 8];

    const float SC = 0.125f * 1.44269504f;   // exp2-domain scaling

    float mstate[4], lstate[4];
    floatx4 oacc[4] = {};
#pragma unroll
    for (int r = 0; r < 4; ++r) { mstate[r] = -__builtin_inff(); lstate[r] = 0.0f; }

    for (int kt = 0; kt <= qb; ++kt) {
        __syncthreads();
#pragma unroll
        for (int p = 0; p < 2; ++p) {
            gl_lds16(Kg + (size_t)kt * 4096 + (size_t)p * 2048,
                     sK + (p * 32 + wave * 8) * 64);
            gl_lds16(Vg + (size_t)kt * 64 + (size_t)p * 32 * 1024,
                     sV + (p * 32 + wave * 8) * 64);
        }
        __syncthreads();

        floatx4 s[4];
#pragma unroll
        for (int nt = 0; nt < 4; ++nt) {
            const int r = nt * 16 + l15;
            const int c0 = quad ^ (r & 7);
            const int c1 = (4 + quad) ^ (r & 7);
            const shortx8 kf0 = *(const shortx8*)&sK[r * 64 + c0 * 8];
            const shortx8 kf1 = *(const shortx8*)&sK[r * 64 + c1 * 8];
            floatx4 z = {};
            z = __builtin_amdgcn_mfma_f32_16x16x32_bf16(qf0, kf0, z, 0, 0, 0);
            z = __builtin_amdgcn_mfma_f32_16x16x32_bf16(qf1, kf1, z, 0, 0, 0);
            s[nt] = z;
        }
#pragma unroll
        for (int nt = 0; nt < 4; ++nt)
#pragma unroll
            for (int r = 0; r < 4; ++r) {
                float sv = s[nt][r] * SC;
                if (kt == qb) {
                    const int col = nt * 16 + l15;
                    const int row = wave * 16 + quad * 4 + r;
                    if (col > row) sv = -__builtin_inff();
                }
                s[nt][r] = sv;
            }
        float mnew[4], alpha[4];
#pragma unroll
        for (int r = 0; r < 4; ++r) {
            float mt = fmaxf(fmaxf(s[0][r], s[1][r]), fmaxf(s[2][r], s[3][r]));
#pragma unroll
            for (int o = 8; o >= 1; o >>= 1) mt = fmaxf(mt, __shfl_xor(mt, o, 64));
            mnew[r]  = fmaxf(mstate[r], mt);
            alpha[r] = exp2f(mstate[r] - mnew[r]);
            mstate[r] = mnew[r];
        }
#pragma unroll
        for (int r = 0; r < 4; ++r) {
            float rs = 0.0f;
#pragma unroll
            for (int nt = 0; nt < 4; ++nt) {
                const float p = exp2f(s[nt][r] - mnew[r]);
                s[nt][r] = p;
                rs += p;
            }
#pragma unroll
            for (int o = 8; o >= 1; o >>= 1) rs += __shfl_xor(rs, o, 64);
            lstate[r] = alpha[r] * lstate[r] + rs;
#pragma unroll
            for (int dt = 0; dt < 4; ++dt) oacc[dt][r] *= alpha[r];
        }
#pragma unroll
        for (int nt = 0; nt < 4; ++nt)
#pragma unroll
            for (int r = 0; r < 4; ++r)
                sP[wave][(quad * 4 + r) * 72 + nt * 16 + l15] = f2b(s[nt][r]);
        __asm__ volatile("s_waitcnt lgkmcnt(0)" ::: "memory");
        const shortx8 pf0 = *(const shortx8*)&sP[wave][l15 * 72 + quad * 8];
        const shortx8 pf1 = *(const shortx8*)&sP[wave][l15 * 72 + 32 + quad * 8];
#pragma unroll
        for (int dt = 0; dt < 4; ++dt) {
            const int r = dt * 16 + l15;
            const int c0 = quad ^ (r & 7);
            const int c1 = (4 + quad) ^ (r & 7);
            const shortx8 v0 = *(const shortx8*)&sV[r * 64 + c0 * 8];
            const shortx8 v1 = *(const shortx8*)&sV[r * 64 + c1 * 8];
            oacc[dt] = __builtin_amdgcn_mfma_f32_16x16x32_bf16(pf0, v0, oacc[dt], 0, 0, 0);
            oacc[dt] = __builtin_amdgcn_mfma_f32_16x16x32_bf16(pf1, v1, oacc[dt], 0, 0, 0);
        }
    }
#pragma unroll
    for (int dt = 0; dt < 4; ++dt)
#pragma unroll
        for (int r = 0; r < 4; ++r) {
            const int t = qb * 64 + wave * 16 + quad * 4 + r;
            const int dim = dt * 16 + l15;
            const float v = oacc[dt][r] / lstate[r];
            ctx[(size_t)(bb * 1024 + t) * 1024 + h * 64 + dim] = f2b(v);
        }
}

// ---------------------------------------------------------------------------
// Launch
// ---------------------------------------------------------------------------
extern "C" void kernel_launch(void* const* d_in, const int* in_sizes, int n_in,
                              void* d_out, int out_size, void* d_ws, size_t ws_size,
                              hipStream_t stream) {
    const float* x    = (const float*)d_in[0];
    const float* ln1w = (const float*)d_in[2];
    const float* ln1b = (const float*)d_in[3];
    const float* ln2w = (const float*)d_in[4];
    const float* ln2b = (const float*)d_in[5];
    const float* wq   = (const float*)d_in[6];
    const float* bq   = (const float*)d_in[7];
    const float* wk   = (const float*)d_in[8];
    const float* bk   = (const float*)d_in[9];
    const float* wv   = (const float*)d_in[10];
    const float* bv   = (const float*)d_in[11];
    const float* wo   = (const float*)d_in[12];
    const float* bo   = (const float*)d_in[13];
    const float* w1   = (const float*)d_in[14];
    const float* b1   = (const float*)d_in[15];
    const float* w2   = (const float*)d_in[16];
    const float* b2   = (const float*)d_in[17];

    char* ws = (char*)d_ws;
    const size_t MB = 1024 * 1024;
    ushort* WQKVT = (ushort*)(ws + 0 * MB);     // [3072][1024] bf16 (wq|wk|wv ^T)
    ushort* WOT   = (ushort*)(ws + 6 * MB);     // [1024][1024]
    ushort* W1T   = (ushort*)(ws + 8 * MB);     // [4096][1024]
    ushort* W2T   = (ushort*)(ws + 16 * MB);    // [1024][4096]
    ushort* H1    = (ushort*)(ws + 24 * MB);    // [8192][1024]; H2 overlays later
    ushort* H2    = H1;
    ushort* Qb    = (ushort*)(ws + 40 * MB);    // [128][1024][64]
    ushort* Kb    = (ushort*)(ws + 56 * MB);    // [128][1024][64]
    ushort* Vbt   = (ushort*)(ws + 72 * MB);    // [128][64][1024]
    ushort* FF1   = (ushort*)(ws + 40 * MB);    // [8192][4096] overlays Q,K,V (dead)
    ushort* CTX   = (ushort*)(ws + 104 * MB);   // [8192][1024]

    float* xout = (float*)d_out;                // x2 lives here, then final out

    const dim3 tb(32, 8);
    transp4_kernel<<<dim3(32, 32, 4), tb, 0, stream>>>(
        wq, wk, wv, wo,
        WQKVT, WQKVT + 1024 * 1024, WQKVT + 2048 * 1024, WOT);
    transp_kernel<<<dim3(128, 32), tb, 0, stream>>>(w1, W1T, 1024, 4096);
    transp_kernel<<<dim3(32, 128), tb, 0, stream>>>(w2, W2T, 4096, 1024);

    ln_kernel<<<8192, 256, 0, stream>>>(x, ln1w, ln1b, H1);

    gemm_bt<1><<<dim3(24, 64), 256, 0, stream>>>(H1, WQKVT, bq, bk, bv,
                                                 Qb, Kb, Vbt, nullptr,
                                                 8192, 3072, 1024);

    attn_kernel<<<2048, 256, 0, stream>>>(Qb, Kb, Vbt, CTX);

    gemm_bt<2><<<dim3(8, 64), 256, 0, stream>>>(CTX, WOT, bo, nullptr, nullptr,
                                                xout, nullptr, nullptr, x,
                                                8192, 1024, 1024);

    ln_kernel<<<8192, 256, 0, stream>>>(xout, ln2w, ln2b, H2);

    gemm_bt<3><<<dim3(32, 64), 256, 0, stream>>>(H2, W1T, b1, nullptr, nullptr,
                                                 FF1, nullptr, nullptr, nullptr,
                                                 8192, 4096, 1024);

    gemm_bt<2><<<dim3(8, 64), 256, 0, stream>>>(FF1, W2T, b2, nullptr, nullptr,
                                                xout, nullptr, nullptr, xout,
                                                8192, 1024, 4096);

    (void)in_sizes; (void)n_in; (void)out_size; (void)ws_size;
}

// Round 5
// 511.708 us; speedup vs baseline: 1.2941x; 1.0109x over previous
//
#include <hip/hip_runtime.h>
#include <hip/hip_bf16.h>
#include <math.h>

// ---------------------------------------------------------------------------
// TransformerBlock: B=8 T=1024 C=1024 H=16 d=64, bf16 MFMA compute, fp32 acc.
// R5: 256x128 tiles for QKV + FFN1 (2x MFMA per staged K-iter, amortizes the
//     16-iteration K-loop prologue); Wo/FFN2 keep the 128x128 kernel.
// ---------------------------------------------------------------------------

#define DEVI __device__ __forceinline__

typedef __attribute__((ext_vector_type(4))) float floatx4;
typedef __attribute__((ext_vector_type(16))) float floatx16;
typedef __attribute__((ext_vector_type(8))) short shortx8;   // 8 bf16 = 4 VGPRs

DEVI ushort f2b(float f) {
    __hip_bfloat16 h = __float2bfloat16(f);
    return __builtin_bit_cast(ushort, h);
}

DEVI void gl_lds16(const ushort* g, ushort* l) {
    // 16B direct global->LDS. LDS dest = wave-uniform base + lane*16.
    __builtin_amdgcn_global_load_lds(
        (const __attribute__((address_space(1))) void*)g,
        (__attribute__((address_space(3))) void*)l, 16, 0, 0);
}

// tanh-form GeLU: |err| vs erf-GeLU ~3e-3 — far under the bf16 threshold.
DEVI float gelu_f(float v) {
    const float u0 = 0.7978845608f * v * (1.0f + 0.044715f * v * v);
    const float u  = fminf(fmaxf(u0, -15.0f), 15.0f);
    const float e  = exp2f(u * 2.885390082f);      // e^{2u}
    const float th = 1.0f - 2.0f / (e + 1.0f);     // tanh(u)
    return 0.5f * v * (1.0f + th);
}

// ---------------------------------------------------------------------------
// Fused transpose of the four 1024x1024 weights (z picks the matrix).
// ---------------------------------------------------------------------------
__global__ void transp4_kernel(const float* __restrict__ s0, const float* __restrict__ s1,
                               const float* __restrict__ s2, const float* __restrict__ s3,
                               ushort* __restrict__ d0, ushort* __restrict__ d1,
                               ushort* __restrict__ d2, ushort* __restrict__ d3) {
    const int z = blockIdx.z;
    const float* src = (z == 0) ? s0 : (z == 1) ? s1 : (z == 2) ? s2 : s3;
    ushort*      dst = (z == 0) ? d0 : (z == 1) ? d1 : (z == 2) ? d2 : d3;
    __shared__ float tile[32][33];
    const int c0 = blockIdx.x * 32, r0 = blockIdx.y * 32;
    const int tx = threadIdx.x, ty = threadIdx.y;   // 32 x 8
#pragma unroll
    for (int i = 0; i < 32; i += 8)
        tile[ty + i][tx] = src[(size_t)(r0 + ty + i) * 1024 + c0 + tx];
    __syncthreads();
#pragma unroll
    for (int i = 0; i < 32; i += 8)
        dst[(size_t)(c0 + ty + i) * 1024 + r0 + tx] = f2b(tile[tx][ty + i]);
}

__global__ void transp_kernel(const float* __restrict__ src,
                              ushort* __restrict__ dst, int R, int C) {
    __shared__ float tile[32][33];
    const int c0 = blockIdx.x * 32, r0 = blockIdx.y * 32;
    const int tx = threadIdx.x, ty = threadIdx.y;   // 32 x 8
#pragma unroll
    for (int i = 0; i < 32; i += 8)
        tile[ty + i][tx] = src[(size_t)(r0 + ty + i) * C + c0 + tx];
    __syncthreads();
#pragma unroll
    for (int i = 0; i < 32; i += 8)
        dst[(size_t)(c0 + ty + i) * R + r0 + tx] = f2b(tile[tx][ty + i]);
}

// ---------------------------------------------------------------------------
// LayerNorm over C=1024, one block (256 thr) per token. fp32 in, bf16 out.
// ---------------------------------------------------------------------------
__global__ __launch_bounds__(256)
void ln_kernel(const float* __restrict__ x, const float* __restrict__ w,
               const float* __restrict__ b, ushort* __restrict__ out) {
    __shared__ float red[8];
    const int m = blockIdx.x;
    const int tid = threadIdx.x;
    const float4 xv = *(const float4*)&x[(size_t)m * 1024 + tid * 4];
    float s  = xv.x + xv.y + xv.z + xv.w;
    float s2 = xv.x * xv.x + xv.y * xv.y + xv.z * xv.z + xv.w * xv.w;
#pragma unroll
    for (int o = 32; o >= 1; o >>= 1) {
        s  += __shfl_xor(s, o, 64);
        s2 += __shfl_xor(s2, o, 64);
    }
    const int wv_ = tid >> 6;
    if ((tid & 63) == 0) { red[wv_] = s; red[4 + wv_] = s2; }
    __syncthreads();
    s  = red[0] + red[1] + red[2] + red[3];
    s2 = red[4] + red[5] + red[6] + red[7];
    const float mu   = s * (1.0f / 1024.0f);
    const float var  = s2 * (1.0f / 1024.0f) - mu * mu;
    const float rstd = rsqrtf(var + 1e-5f);
    const float4 wv = *(const float4*)&w[tid * 4];
    const float4 bv = *(const float4*)&b[tid * 4];
    ushort o4[4];
    o4[0] = f2b((xv.x - mu) * rstd * wv.x + bv.x);
    o4[1] = f2b((xv.y - mu) * rstd * wv.y + bv.y);
    o4[2] = f2b((xv.z - mu) * rstd * wv.z + bv.z);
    o4[3] = f2b((xv.w - mu) * rstd * wv.w + bv.w);
    *(uint2*)&out[(size_t)m * 1024 + tid * 4] = *(uint2*)o4;
}

// ---------------------------------------------------------------------------
// BIG GEMM: 256(M) x 128(N) tile, BK=64. 4 waves, each 128x64 via 4x2 of
// mfma_32x32x16_bf16 (acc = 8 x floatx16 = 128 AGPR). 2 waves/SIMD target.
//   MODE 1: fused QKV  (Q / K heads layout, V^T via wave-parity LDS transpose)
//   MODE 3: bf16 out = gelu(acc + bias)
// Staging identical swizzle discipline to the 128^2 kernel.
// ---------------------------------------------------------------------------
template <int MODE>
__global__ __launch_bounds__(256, 2)
void gemm_big(const ushort* __restrict__ A, const ushort* __restrict__ Bt,
              const float* __restrict__ biasQ, const float* __restrict__ biasK,
              const float* __restrict__ biasV,
              void* __restrict__ out, void* __restrict__ out2, void* __restrict__ out3,
              int N, int K) {
    __shared__ ushort lds[(256 + 128) * 64];   // 48 KB: sA 256x64, sB 128x64
    ushort* sA = lds;
    ushort* sB = lds + 256 * 64;

    const int tid  = threadIdx.x;
    const int lane = tid & 63;
    const int wave = tid >> 6;
    const int l31  = lane & 31;
    const int half = lane >> 5;
    const int wm   = (wave & 1) * 128;
    const int wn   = (wave >> 1) * 64;
    const int m0   = blockIdx.y * 256;
    const int n0   = blockIdx.x * 128;

    floatx16 acc[4][2] = {};

    const int lrow = lane >> 3;          // 0..7
    const int scb  = (lane & 7) ^ lrow;  // swizzled SOURCE col-block
    const ushort* Ag = A  + (size_t)(m0 + wave * 8 + lrow) * K + scb * 8;
    const ushort* Bg = Bt + (size_t)(n0 + wave * 8 + lrow) * K + scb * 8;

    for (int k0 = 0; k0 < K; k0 += 64) {
        __syncthreads();
#pragma unroll
        for (int p = 0; p < 8; ++p)
            gl_lds16(Ag + (size_t)(p * 32) * K + k0, sA + (p * 32 + wave * 8) * 64);
#pragma unroll
        for (int p = 0; p < 4; ++p)
            gl_lds16(Bg + (size_t)(p * 32) * K + k0, sB + (p * 32 + wave * 8) * 64);
        __syncthreads();
#pragma unroll
        for (int ks = 0; ks < 4; ++ks) {
            const int cx = ks * 2 + half;
            shortx8 af[4], bf[2];
#pragma unroll
            for (int i = 0; i < 4; ++i) {
                const int r = wm + i * 32 + l31;
                af[i] = *(const shortx8*)&sA[r * 64 + (cx ^ (r & 7)) * 8];
            }
#pragma unroll
            for (int j = 0; j < 2; ++j) {
                const int r = wn + j * 32 + l31;
                bf[j] = *(const shortx8*)&sB[r * 64 + (cx ^ (r & 7)) * 8];
            }
#pragma unroll
            for (int i = 0; i < 4; ++i)
#pragma unroll
                for (int j = 0; j < 2; ++j)
                    acc[i][j] = __builtin_amdgcn_mfma_f32_32x32x16_bf16(
                        af[i], bf[j], acc[i][j], 0, 0, 0);
        }
    }

    if constexpr (MODE == 1) {
        const int mat = n0 >> 10;   // block-uniform (128 | 1024)
        if (mat < 2) {
            const float* bp = (mat == 0) ? biasQ : biasK;
            ushort* dst = (mat == 0) ? (ushort*)out : (ushort*)out2;
            const int bb = m0 >> 10;          // 256-tile within one batch row
            const int tbase = m0 & 1023;
#pragma unroll
            for (int i = 0; i < 4; ++i)
#pragma unroll
                for (int j = 0; j < 2; ++j) {
                    const int cn = (n0 & 1023) + wn + j * 32 + l31;
                    const float bv = bp[cn];
                    const int h = cn >> 6, dd = cn & 63;
#pragma unroll
                    for (int reg = 0; reg < 16; ++reg) {
                        const int t = tbase + wm + i * 32 + (reg & 3) + 8 * (reg >> 2) + 4 * half;
                        dst[((size_t)(bb * 16 + h) * 1024 + t) * 64 + dd] =
                            f2b(acc[i][j][reg] + bv);
                    }
                }
        } else {
            // V: wave-parity halves through a 128x136 LDS transpose tile
            ushort* T = lds;
            const int vb = n0 - 2048;
            const int bb = m0 >> 10;
#pragma unroll
            for (int hf = 0; hf < 2; ++hf) {
                __syncthreads();
                if ((wave & 1) == hf) {
#pragma unroll
                    for (int i = 0; i < 4; ++i)
#pragma unroll
                        for (int j = 0; j < 2; ++j) {
                            const int dim = wn + j * 32 + l31;   // 0..127 local
                            const float bv = biasV[vb + dim];
#pragma unroll
                            for (int rq = 0; rq < 4; ++rq) {
                                const int tloc = i * 32 + 8 * rq + 4 * half;
                                ushort pk[4];
#pragma unroll
                                for (int e = 0; e < 4; ++e)
                                    pk[e] = f2b(acc[i][j][rq * 4 + e] + bv);
                                *(uint2*)&T[dim * 136 + tloc] = *(uint2*)pk;
                            }
                        }
                }
                __syncthreads();
#pragma unroll
                for (int pass = 0; pass < 8; ++pass) {
                    const int row = pass * 16 + (tid >> 4);   // dim-local 0..127
                    const int cb  = (tid & 15) * 8;           // t-local chunk
                    const uint4 val = *(const uint4*)&T[row * 136 + cb];
                    const int dd = vb + row;
                    const int h = dd >> 6, dl = dd & 63;
                    const int t = (m0 & 1023) + hf * 128 + cb;
                    *(uint4*)&((ushort*)out3)[((size_t)(bb * 16 + h) * 64 + dl) * 1024 + t] = val;
                }
            }
        }
    } else {   // MODE 3: gelu
#pragma unroll
        for (int i = 0; i < 4; ++i)
#pragma unroll
            for (int j = 0; j < 2; ++j) {
                const int gn = n0 + wn + j * 32 + l31;
                const float bv = biasQ[gn];
#pragma unroll
                for (int reg = 0; reg < 16; ++reg) {
                    const int gm = m0 + wm + i * 32 + (reg & 3) + 8 * (reg >> 2) + 4 * half;
                    const float v = acc[i][j][reg] + bv;
                    ((ushort*)out)[(size_t)gm * N + gn] = f2b(gelu_f(v));
                }
            }
    }
}

// ---------------------------------------------------------------------------
// 128x128 GEMM (MODE 2 only): fp32 out = resid + acc + bias. Wo / FFN2.
// ---------------------------------------------------------------------------
__global__ __launch_bounds__(256)
void gemm_res(const ushort* __restrict__ A, const ushort* __restrict__ Bt,
              const float* __restrict__ bias, float* __restrict__ out,
              const float* __restrict__ resid, int N, int K) {
    __shared__ ushort lds[128 * 64 * 2];
    ushort* sA = lds;
    ushort* sB = lds + 128 * 64;

    const int tid  = threadIdx.x;
    const int lane = tid & 63;
    const int wave = tid >> 6;
    const int l31  = lane & 31;
    const int half = lane >> 5;
    const int wm   = (wave & 1) * 64;
    const int wn   = (wave >> 1) * 64;
    const int m0   = blockIdx.y * 128;
    const int n0   = blockIdx.x * 128;

    floatx16 acc[2][2] = {};

    const int lrow = lane >> 3;
    const int scb  = (lane & 7) ^ lrow;
    const ushort* Ag = A  + (size_t)(m0 + wave * 8 + lrow) * K + scb * 8;
    const ushort* Bg = Bt + (size_t)(n0 + wave * 8 + lrow) * K + scb * 8;

    for (int k0 = 0; k0 < K; k0 += 64) {
        __syncthreads();
#pragma unroll
        for (int p = 0; p < 4; ++p) {
            gl_lds16(Ag + (size_t)(p * 32) * K + k0, sA + (p * 32 + wave * 8) * 64);
            gl_lds16(Bg + (size_t)(p * 32) * K + k0, sB + (p * 32 + wave * 8) * 64);
        }
        __syncthreads();
#pragma unroll
        for (int ks = 0; ks < 4; ++ks) {
            const int cx = ks * 2 + half;
            shortx8 af[2], bf[2];
#pragma unroll
            for (int i = 0; i < 2; ++i) {
                const int r = wm + i * 32 + l31;
                af[i] = *(const shortx8*)&sA[r * 64 + (cx ^ (r & 7)) * 8];
            }
#pragma unroll
            for (int j = 0; j < 2; ++j) {
                const int r = wn + j * 32 + l31;
                bf[j] = *(const shortx8*)&sB[r * 64 + (cx ^ (r & 7)) * 8];
            }
#pragma unroll
            for (int i = 0; i < 2; ++i)
#pragma unroll
                for (int j = 0; j < 2; ++j)
                    acc[i][j] = __builtin_amdgcn_mfma_f32_32x32x16_bf16(
                        af[i], bf[j], acc[i][j], 0, 0, 0);
        }
    }
#pragma unroll
    for (int i = 0; i < 2; ++i)
#pragma unroll
        for (int j = 0; j < 2; ++j) {
            const int gn = n0 + wn + j * 32 + l31;
            const float bv = bias[gn];
#pragma unroll
            for (int reg = 0; reg < 16; ++reg) {
                const int gm = m0 + wm + i * 32 + (reg & 3) + 8 * (reg >> 2) + 4 * half;
                out[(size_t)gm * N + gn] =
                    acc[i][j][reg] + bv + resid[(size_t)gm * N + gn];
            }
        }
}

// ---------------------------------------------------------------------------
// Flash-style causal attention, LDS-staged (unchanged from R4).
// ---------------------------------------------------------------------------
__global__ __launch_bounds__(256)
void attn_kernel(const ushort* __restrict__ Q, const ushort* __restrict__ Kk,
                 const ushort* __restrict__ Vt, ushort* __restrict__ ctx) {
    __shared__ ushort sK[64 * 64];
    __shared__ ushort sV[64 * 64];     // V^T tile: [d][64 kv-cols]
    __shared__ ushort sP[4][16 * 72];

    const int tid  = threadIdx.x;
    const int lane = tid & 63;
    const int wave = tid >> 6;
    const int quad = lane >> 4;
    const int l15  = lane & 15;

    const int qb = 15 - (blockIdx.x >> 7);   // descending workload
    const int bh = blockIdx.x & 127;
    const size_t base = (size_t)bh << 16;    // bh*1024*64
    const int bb = bh >> 4, h = bh & 15;

    const int lrow = lane >> 3;
    const int scb  = (lane & 7) ^ lrow;
    const ushort* Kg = Kk + base + (size_t)(wave * 8 + lrow) * 64 + scb * 8;
    const ushort* Vg = Vt + base + (size_t)(wave * 8 + lrow) * 1024 + scb * 8;

    const int qrow = qb * 64 + wave * 16 + l15;
    const shortx8 qf0 = *(const shortx8*)&Q[base + (size_t)qrow * 64 + quad * 8];
    const shortx8 qf1 = *(const shortx8*)&Q[base + (size_t)qrow * 64 + 32 + quad * 8];

    const float SC = 0.125f * 1.44269504f;   // exp2-domain scaling

    float mstate[4], lstate[4];
    floatx4 oacc[4] = {};
#pragma unroll
    for (int r = 0; r < 4; ++r) { mstate[r] = -__builtin_inff(); lstate[r] = 0.0f; }

    for (int kt = 0; kt <= qb; ++kt) {
        __syncthreads();
#pragma unroll
        for (int p = 0; p < 2; ++p) {
            gl_lds16(Kg + (size_t)kt * 4096 + (size_t)p * 2048,
                     sK + (p * 32 + wave * 8) * 64);
            gl_lds16(Vg + (size_t)kt * 64 + (size_t)p * 32 * 1024,
                     sV + (p * 32 + wave * 8) * 64);
        }
        __syncthreads();

        floatx4 s[4];
#pragma unroll
        for (int nt = 0; nt < 4; ++nt) {
            const int r = nt * 16 + l15;
            const int c0 = quad ^ (r & 7);
            const int c1 = (4 + quad) ^ (r & 7);
            const shortx8 kf0 = *(const shortx8*)&sK[r * 64 + c0 * 8];
            const shortx8 kf1 = *(const shortx8*)&sK[r * 64 + c1 * 8];
            floatx4 z = {};
            z = __builtin_amdgcn_mfma_f32_16x16x32_bf16(qf0, kf0, z, 0, 0, 0);
            z = __builtin_amdgcn_mfma_f32_16x16x32_bf16(qf1, kf1, z, 0, 0, 0);
            s[nt] = z;
        }
#pragma unroll
        for (int nt = 0; nt < 4; ++nt)
#pragma unroll
            for (int r = 0; r < 4; ++r) {
                float sv = s[nt][r] * SC;
                if (kt == qb) {
                    const int col = nt * 16 + l15;
                    const int row = wave * 16 + quad * 4 + r;
                    if (col > row) sv = -__builtin_inff();
                }
                s[nt][r] = sv;
            }
        float mnew[4], alpha[4];
#pragma unroll
        for (int r = 0; r < 4; ++r) {
            float mt = fmaxf(fmaxf(s[0][r], s[1][r]), fmaxf(s[2][r], s[3][r]));
#pragma unroll
            for (int o = 8; o >= 1; o >>= 1) mt = fmaxf(mt, __shfl_xor(mt, o, 64));
            mnew[r]  = fmaxf(mstate[r], mt);
            alpha[r] = exp2f(mstate[r] - mnew[r]);
            mstate[r] = mnew[r];
        }
#pragma unroll
        for (int r = 0; r < 4; ++r) {
            float rs = 0.0f;
#pragma unroll
            for (int nt = 0; nt < 4; ++nt) {
                const float p = exp2f(s[nt][r] - mnew[r]);
                s[nt][r] = p;
                rs += p;
            }
#pragma unroll
            for (int o = 8; o >= 1; o >>= 1) rs += __shfl_xor(rs, o, 64);
            lstate[r] = alpha[r] * lstate[r] + rs;
#pragma unroll
            for (int dt = 0; dt < 4; ++dt) oacc[dt][r] *= alpha[r];
        }
#pragma unroll
        for (int nt = 0; nt < 4; ++nt)
#pragma unroll
            for (int r = 0; r < 4; ++r)
                sP[wave][(quad * 4 + r) * 72 + nt * 16 + l15] = f2b(s[nt][r]);
        __asm__ volatile("s_waitcnt lgkmcnt(0)" ::: "memory");
        const shortx8 pf0 = *(const shortx8*)&sP[wave][l15 * 72 + quad * 8];
        const shortx8 pf1 = *(const shortx8*)&sP[wave][l15 * 72 + 32 + quad * 8];
#pragma unroll
        for (int dt = 0; dt < 4; ++dt) {
            const int r = dt * 16 + l15;
            const int c0 = quad ^ (r & 7);
            const int c1 = (4 + quad) ^ (r & 7);
            const shortx8 v0 = *(const shortx8*)&sV[r * 64 + c0 * 8];
            const shortx8 v1 = *(const shortx8*)&sV[r * 64 + c1 * 8];
            oacc[dt] = __builtin_amdgcn_mfma_f32_16x16x32_bf16(pf0, v0, oacc[dt], 0, 0, 0);
            oacc[dt] = __builtin_amdgcn_mfma_f32_16x16x32_bf16(pf1, v1, oacc[dt], 0, 0, 0);
        }
    }
#pragma unroll
    for (int dt = 0; dt < 4; ++dt)
#pragma unroll
        for (int r = 0; r < 4; ++r) {
            const int t = qb * 64 + wave * 16 + quad * 4 + r;
            const int dim = dt * 16 + l15;
            const float v = oacc[dt][r] / lstate[r];
            ctx[(size_t)(bb * 1024 + t) * 1024 + h * 64 + dim] = f2b(v);
        }
}

// ---------------------------------------------------------------------------
// Launch
// ---------------------------------------------------------------------------
extern "C" void kernel_launch(void* const* d_in, const int* in_sizes, int n_in,
                              void* d_out, int out_size, void* d_ws, size_t ws_size,
                              hipStream_t stream) {
    const float* x    = (const float*)d_in[0];
    const float* ln1w = (const float*)d_in[2];
    const float* ln1b = (const float*)d_in[3];
    const float* ln2w = (const float*)d_in[4];
    const float* ln2b = (const float*)d_in[5];
    const float* wq   = (const float*)d_in[6];
    const float* bq   = (const float*)d_in[7];
    const float* wk   = (const float*)d_in[8];
    const float* bk   = (const float*)d_in[9];
    const float* wv   = (const float*)d_in[10];
    const float* bv   = (const float*)d_in[11];
    const float* wo   = (const float*)d_in[12];
    const float* bo   = (const float*)d_in[13];
    const float* w1   = (const float*)d_in[14];
    const float* b1   = (const float*)d_in[15];
    const float* w2   = (const float*)d_in[16];
    const float* b2   = (const float*)d_in[17];

    char* ws = (char*)d_ws;
    const size_t MB = 1024 * 1024;
    ushort* WQKVT = (ushort*)(ws + 0 * MB);     // [3072][1024] bf16 (wq|wk|wv ^T)
    ushort* WOT   = (ushort*)(ws + 6 * MB);     // [1024][1024]
    ushort* W1T   = (ushort*)(ws + 8 * MB);     // [4096][1024]
    ushort* W2T   = (ushort*)(ws + 16 * MB);    // [1024][4096]
    ushort* H1    = (ushort*)(ws + 24 * MB);    // [8192][1024]; H2 overlays later
    ushort* H2    = H1;
    ushort* Qb    = (ushort*)(ws + 40 * MB);    // [128][1024][64]
    ushort* Kb    = (ushort*)(ws + 56 * MB);    // [128][1024][64]
    ushort* Vbt   = (ushort*)(ws + 72 * MB);    // [128][64][1024]
    ushort* FF1   = (ushort*)(ws + 40 * MB);    // [8192][4096] overlays Q,K,V (dead)
    ushort* CTX   = (ushort*)(ws + 104 * MB);   // [8192][1024]

    float* xout = (float*)d_out;                // x2 lives here, then final out

    const dim3 tb(32, 8);
    transp4_kernel<<<dim3(32, 32, 4), tb, 0, stream>>>(
        wq, wk, wv, wo,
        WQKVT, WQKVT + 1024 * 1024, WQKVT + 2048 * 1024, WOT);
    transp_kernel<<<dim3(128, 32), tb, 0, stream>>>(w1, W1T, 1024, 4096);
    transp_kernel<<<dim3(32, 128), tb, 0, stream>>>(w2, W2T, 4096, 1024);

    ln_kernel<<<8192, 256, 0, stream>>>(x, ln1w, ln1b, H1);

    gemm_big<1><<<dim3(24, 32), 256, 0, stream>>>(H1, WQKVT, bq, bk, bv,
                                                  Qb, Kb, Vbt, 3072, 1024);

    attn_kernel<<<2048, 256, 0, stream>>>(Qb, Kb, Vbt, CTX);

    gemm_res<<<dim3(8, 64), 256, 0, stream>>>(CTX, WOT, bo, xout, x, 1024, 1024);

    ln_kernel<<<8192, 256, 0, stream>>>(xout, ln2w, ln2b, H2);

    gemm_big<3><<<dim3(32, 32), 256, 0, stream>>>(H2, W1T, b1, nullptr, nullptr,
                                                  FF1, nullptr, nullptr, 4096, 1024);

    gemm_res<<<dim3(8, 64), 256, 0, stream>>>(FF1, W2T, b2, xout, xout, 1024, 4096);

    (void)in_sizes; (void)n_in; (void)out_size; (void)ws_size;
}